// Round 13
// baseline (257.806 us; speedup 1.0000x reference)
//
#include <hip/hip_runtime.h>
#include <cstdint>

// ---------------------------------------------------------------------------
// GroupedQueryAttention: B=2 N=2048 DIM=2048 HQ=16 HKV=4 HD=128, causal, RoPE.
// f32 I/O, bf16 internals. Round 13:
//  - GEMMs: BK=128 (16 rounds, 32 MFMA/round/wave) + A-register prefetch one
//    round ahead (f32 load latency hidden under compute, no extra LDS).
//    64x128 tile, LDS 48KB, 3 blocks/CU.
//  - attention / rope / transpose unchanged from round 12.
// ---------------------------------------------------------------------------

typedef __bf16 bf16_t;
typedef __attribute__((ext_vector_type(8))) __bf16 bf16x8;
typedef __attribute__((ext_vector_type(4))) float f32x4;

#define B_    2
#define N_    2048
#define DIM_  2048
#define HQ_   16
#define HKV_  4
#define HD_   128
#define KVD_  512
#define SCALE_ 0.08838834764831845f  // 128^-0.5

// async global->LDS, 16B per lane. lds dest must be wave-uniform base.
static __device__ __forceinline__ void ld_g2l(void* lds, const void* g) {
  __builtin_amdgcn_global_load_lds((__attribute__((address_space(1))) void*)g,
                                   (__attribute__((address_space(3))) void*)lds,
                                   16, 0, 0);
}

static __device__ __forceinline__ f32x4 vmax4(f32x4 a, f32x4 b) {
  f32x4 r;
  r[0] = fmaxf(a[0], b[0]); r[1] = fmaxf(a[1], b[1]);
  r[2] = fmaxf(a[2], b[2]); r[3] = fmaxf(a[3], b[3]);
  return r;
}

// ---------------------------------------------------------------------------
// cos/sin table: [2048][64] each, f32.  inv_freq = 10000^(-i/64) (base_adj==1)
// ---------------------------------------------------------------------------
__global__ void k_sincos(float* __restrict__ cosT, float* __restrict__ sinT) {
  int idx = blockIdx.x * 256 + threadIdx.x;  // 2048*64
  int i = idx & 63;
  int n = idx >> 6;
  float inv = expf(-(float)i * (9.210340371976184f / 64.0f));  // ln(1e4)/64
  float ang = (float)n * inv;
  cosT[idx] = cosf(ang);
  sinT[idx] = sinf(ang);
}

// ---------------------------------------------------------------------------
// fused f32 -> bf16 conversion for up to three tensors (4 elems/thread)
// ---------------------------------------------------------------------------
__global__ void k_cvt3(const float* __restrict__ s0, bf16_t* __restrict__ d0, int n0,
                       const float* __restrict__ s1, bf16_t* __restrict__ d1, int n1,
                       const float* __restrict__ s2, bf16_t* __restrict__ d2, int n2)
{
  int i = (blockIdx.x * 256 + threadIdx.x) * 4;
  const float* s; bf16_t* d; int off;
  if (i < n0)                { s = s0; d = d0; off = i; }
  else if (i < n0 + n1)      { s = s1; d = d1; off = i - n0; }
  else if (i < n0 + n1 + n2) { s = s2; d = d2; off = i - n0 - n1; }
  else return;
  f32x4 v = *(const f32x4*)(s + off);
  union { bf16_t h[4]; uint2 u; } pk;
  pk.h[0] = (bf16_t)v[0]; pk.h[1] = (bf16_t)v[1];
  pk.h[2] = (bf16_t)v[2]; pk.h[3] = (bf16_t)v[3];
  *(uint2*)(d + off) = pk.u;
}

// ---------------------------------------------------------------------------
// GEMM body, 64(M)x128(N) tile, BK=128: C = A @ W^T + bias.
// A f32 reg-prefetched one round ahead (AMODE=0) or bf16 g2l (AMODE=1);
// W bf16 g2l; C f32 (CF32) or bf16. 4 waves, each 32x64 output (2x4 frags,
// 4 kk sub-steps). LDS: As[64][128] + Bs[128][128] bf16 = 48KB.
// XOR swizzle byte^((row&7)<<4) on 256B rows.
// ---------------------------------------------------------------------------
template <int AMODE, bool CF32>
static __device__ __forceinline__ void gemm_body(
    const void* __restrict__ Av, const bf16_t* __restrict__ W,
    const float* __restrict__ bias, void* __restrict__ Cv,
    int N, int K, int bm, int bn, bf16_t* As, bf16_t* Bs)
{
  const int tid  = threadIdx.x;
  const int lane = tid & 63;
  const int wave = tid >> 6;
  const int l15  = lane & 15;
  const int lg   = lane >> 4;
  const int wr = (wave >> 1) * 32, wc = (wave & 1) * 64;

  f32x4 acc[2][4] = {};

  uint8_t* AsB = (uint8_t*)As;
  uint8_t* BsB = (uint8_t*)Bs;
  const uint8_t* Wbase = (const uint8_t*)W + (size_t)(bn * 128) * K * 2;
  const uint8_t* AbaseB = (const uint8_t*)Av + (size_t)(bm * 64) * K * 2; // bf16 case
  const float*   Af = (const float*)Av;

  f32x4 areg[8];   // A f32 prefetch (32 elems/thread)

  auto loadA = [&](int k0) {
#pragma unroll
    for (int i = 0; i < 4; ++i) {
      int c = i * 256 + tid;
      int row = c >> 4;            // 0..63
      int k8  = (c & 15) * 8;      // elem offset within 128-elem K-tile
      const float* ap = Af + (size_t)(bm * 64 + row) * K + k0 + k8;
      areg[i * 2]     = *(const f32x4*)ap;
      areg[i * 2 + 1] = *(const f32x4*)(ap + 4);
    }
  };
  auto writeA = [&]() {
#pragma unroll
    for (int i = 0; i < 4; ++i) {
      int c = i * 256 + tid;
      int row = c >> 4;
      int k8  = (c & 15) * 8;
      bf16x8 va;
      f32x4 lo = areg[i * 2], hi = areg[i * 2 + 1];
      va[0] = (bf16_t)lo[0]; va[1] = (bf16_t)lo[1];
      va[2] = (bf16_t)lo[2]; va[3] = (bf16_t)lo[3];
      va[4] = (bf16_t)hi[0]; va[5] = (bf16_t)hi[1];
      va[6] = (bf16_t)hi[2]; va[7] = (bf16_t)hi[3];
      int sw = (k8 * 2) ^ ((row & 7) << 4);
      *(bf16x8*)(AsB + row * 256 + sw) = va;
    }
  };
  auto stageW = [&](int k0) {
#pragma unroll
    for (int r = 0; r < 8; ++r) {
      int o = r * 4096 + wave * 1024 + lane * 16;
      int row = o >> 8;
      int colB = (o & 255) ^ ((row & 7) << 4);
      ld_g2l(BsB + r * 4096 + wave * 1024,
             Wbase + (size_t)row * (K * 2) + (size_t)k0 * 2 + colB);
    }
  };
  auto stageA_g2l = [&](int k0) {
#pragma unroll
    for (int r = 0; r < 4; ++r) {
      int o = r * 4096 + wave * 1024 + lane * 16;
      int row = o >> 8;
      int colB = (o & 255) ^ ((row & 7) << 4);
      ld_g2l(AsB + r * 4096 + wave * 1024,
             AbaseB + (size_t)row * (K * 2) + (size_t)k0 * 2 + colB);
    }
  };

  if (AMODE == 0) loadA(0);

  for (int k0 = 0; k0 < K; k0 += 128) {
    stageW(k0);                                  // async g2l
    if (AMODE == 0) writeA();                    // waits only on areg
    else            stageA_g2l(k0);
    __syncthreads();                             // staging visible/drained
    if (AMODE == 0 && k0 + 128 < K) loadA(k0 + 128);  // issue early; hidden
                                                 // under compute below
    __builtin_amdgcn_s_setprio(1);
#pragma unroll
    for (int kk = 0; kk < 4; ++kk) {
      const int koff = kk * 64 + (lg << 4);
      bf16x8 fa[2], fb[4];
#pragma unroll
      for (int fi = 0; fi < 2; ++fi) {
        int row = wr + fi * 16 + l15;
        fa[fi] = *(const bf16x8*)(AsB + row * 256 + (koff ^ ((row & 7) << 4)));
      }
#pragma unroll
      for (int fj = 0; fj < 4; ++fj) {
        int row = wc + fj * 16 + l15;
        fb[fj] = *(const bf16x8*)(BsB + row * 256 + (koff ^ ((row & 7) << 4)));
      }
#pragma unroll
      for (int fi = 0; fi < 2; ++fi)
#pragma unroll
        for (int fj = 0; fj < 4; ++fj)
          acc[fi][fj] = __builtin_amdgcn_mfma_f32_16x16x32_bf16(
              fa[fi], fb[fj], acc[fi][fj], 0, 0, 0);
    }
    __builtin_amdgcn_s_setprio(0);
    __syncthreads();                             // tile reads done
  }

  // epilogue: C/D layout col=lane&15, row=(lane>>4)*4+r
  const int r0 = lg * 4;
#pragma unroll
  for (int fi = 0; fi < 2; ++fi) {
#pragma unroll
    for (int rr = 0; rr < 4; ++rr) {
      int grow = bm * 64 + wr + fi * 16 + r0 + rr;
      size_t rowoff = (size_t)grow * N;
#pragma unroll
      for (int fj = 0; fj < 4; ++fj) {
        int gcol = bn * 128 + wc + fj * 16 + l15;
        float v = acc[fi][fj][rr] + bias[gcol];
        if (CF32) ((float*)Cv)[rowoff + gcol] = v;
        else      ((bf16_t*)Cv)[rowoff + gcol] = (bf16_t)v;
      }
    }
  }
}

// QKV projections in one launch: z=0 Q (N=2048), z=1 K, z=2 V (N=512, bn<4)
__global__ __launch_bounds__(256, 3) void k_gemm_qkv(
    const float* __restrict__ q, const bf16_t* __restrict__ Wqb,
    const float* __restrict__ bq, bf16_t* __restrict__ Qp,
    const float* __restrict__ k, const bf16_t* __restrict__ Wkb,
    const float* __restrict__ bk, bf16_t* __restrict__ Kp,
    const float* __restrict__ v, const bf16_t* __restrict__ Wvb,
    const float* __restrict__ bv, bf16_t* __restrict__ Vp)
{
  __shared__ bf16_t As[64 * 128];
  __shared__ bf16_t Bs[128 * 128];
  const int z = blockIdx.z;
  if (z != 0 && blockIdx.y >= 4) return;
  const float* A; const bf16_t* W; const float* bias; bf16_t* C; int Nn;
  if (z == 0)      { A = q; W = Wqb; bias = bq; C = Qp; Nn = 2048; }
  else if (z == 1) { A = k; W = Wkb; bias = bk; C = Kp; Nn = 512; }
  else             { A = v; W = Wvb; bias = bv; C = Vp; Nn = 512; }
  gemm_body<0, false>(A, W, bias, C, Nn, 2048, blockIdx.x, blockIdx.y, As, Bs);
}

// O projection: A bf16 g2l, C f32
__global__ __launch_bounds__(256, 3) void k_gemm_o(
    const bf16_t* __restrict__ Ain, const bf16_t* __restrict__ Wob,
    const float* __restrict__ bo, float* __restrict__ out)
{
  __shared__ bf16_t As[64 * 128];
  __shared__ bf16_t Bs[128 * 128];
  gemm_body<1, true>(Ain, Wob, bo, out, 2048, 2048, blockIdx.x, blockIdx.y, As, Bs);
}

// ---------------------------------------------------------------------------
// RoPE in-place on X:[4096][nheads*128] bf16, vectorized: each thread handles
// 8 consecutive d (uint4) + partners at d+64. lgnh = log2(nheads). outScale
// folds softmax scale into Q. Threads per (row,head) = 8.
// ---------------------------------------------------------------------------
__global__ void k_rope(bf16_t* __restrict__ X, const float* __restrict__ cosT,
                       const float* __restrict__ sinT, int lgnh, float outScale)
{
  int idx = blockIdx.x * 256 + threadIdx.x;
  int j = idx & 7;                       // d0 = j*8
  int h = (idx >> 3) & ((1 << lgnh) - 1);
  int row = idx >> (3 + lgnh);
  int n = row & (N_ - 1);
  int d0 = j * 8;
  const float* cp = cosT + (n << 6) + d0;
  const float* sp = sinT + (n << 6) + d0;
  f32x4 c0 = *(const f32x4*)cp,  c1 = *(const f32x4*)(cp + 4);
  f32x4 s0 = *(const f32x4*)sp,  s1 = *(const f32x4*)(sp + 4);
  bf16_t* xb = X + (size_t)row * (size_t)(128 << lgnh) + (h << 7) + d0;
  bf16x8 x1 = *(const bf16x8*)xb;
  bf16x8 x2 = *(const bf16x8*)(xb + 64);
  bf16x8 o1, o2;
#pragma unroll
  for (int e = 0; e < 8; ++e) {
    float c = e < 4 ? c0[e] : c1[e - 4];
    float s = e < 4 ? s0[e] : s1[e - 4];
    float a = (float)x1[e], bvl = (float)x2[e];
    o1[e] = (bf16_t)((a * c - bvl * s) * outScale);
    o2[e] = (bf16_t)((bvl * c + a * s) * outScale);
  }
  *(bf16x8*)xb = o1;
  *(bf16x8*)(xb + 64) = o2;
}

// ---------------------------------------------------------------------------
// Vp:[4096][512] -> Vt:[B*HKV][128][2048]  (Vt[bh][d][n] = Vp[b*2048+n][hkv*128+d])
// ---------------------------------------------------------------------------
__global__ void k_transpose_v(const bf16_t* __restrict__ Vp, bf16_t* __restrict__ Vt)
{
  __shared__ bf16_t tile[64][72];
  const int tid = threadIdx.x;
  const int r0 = blockIdx.x * 64;  // global row (b*2048+n)
  const int d0 = blockIdx.y * 64;  // col in [0,512)
  for (int r = 0; r < 2; ++r) {
    int n = r * 32 + (tid >> 3);
    int dc = (tid & 7) * 8;
    *(uint4*)&tile[n][dc] = *(const uint4*)(Vp + (size_t)(r0 + n) * KVD_ + d0 + dc);
  }
  __syncthreads();
  const int b = r0 >> 11;
  const int nseq = r0 & (N_ - 1);
  for (int r = 0; r < 2; ++r) {
    int dd = r * 32 + (tid >> 3);
    int nc = (tid & 7) * 8;
    int dglob = d0 + dd;
    int hkv = dglob >> 7, dloc = dglob & 127;
    union { bf16_t h[8]; uint4 v; } pk;
    for (int j = 0; j < 8; ++j) pk.h[j] = tile[nc + j][dd];
    size_t drow = (size_t)(b * HKV_ + hkv) * 128 + dloc;
    *(uint4*)(Vt + drow * N_ + nseq + nc) = pk.v;
  }
}

// ---------------------------------------------------------------------------
// Flash attention, causal GQA. Grid (16, B*HQ); bx = 15-blockIdx.x (LPT:
// heaviest first). Block = 4 waves owning qtiles 4*bx..4*bx+3 of ONE (b,hq).
// Double-buffered K/V staging: stage(t+1) -> compute(t) -> ONE barrier.
// Swapped-operand MFMA: S^T = mfma(K,Q) -> query=l15, lane-local softmax;
// PV = mfma(V,P), pf in regs. setprio(1) around MFMA clusters. Output
// in-place into Qp.
// ---------------------------------------------------------------------------
__global__ __launch_bounds__(256, 2) void k_attn(
    const bf16_t* __restrict__ Qp, const bf16_t* __restrict__ Kp,
    const bf16_t* __restrict__ Vt, bf16_t* __restrict__ AO)
{
  __shared__ bf16_t Ks[2][64 * 128];
  __shared__ bf16_t Vs[2][128 * 64];
  __shared__ bf16_t Ps[4][16 * 72];
  const int tid = threadIdx.x, lane = tid & 63, wave = tid >> 6;
  const int l15 = lane & 15, lg = lane >> 4;
  const int bx = 15 - (int)blockIdx.x;       // LPT: heavy blocks dispatch first
  const int qtile = bx * 4 + wave;
  const int bh = blockIdx.y;
  const int b = bh >> 4, hq = bh & 15, hkv = hq >> 2;

  // Q fragments: 2 row-frags x 4 k-steps (RoPE'd, scale folded)
  bf16x8 qf[2][4];
  for (int rf = 0; rf < 2; ++rf) {
    size_t qrow = (size_t)b * N_ + qtile * 32 + rf * 16 + l15;
    const uint8_t* qb = (const uint8_t*)Qp + (qrow * DIM_ + (size_t)hq * HD_) * 2 + lg * 16;
    for (int ks = 0; ks < 4; ++ks)
      qf[rf][ks] = *(const bf16x8*)(qb + ks * 64);
  }

  float m[2] = {-1e30f, -1e30f};
  float ln[2] = {0.f, 0.f};
  f32x4 o[2][8] = {};   // o[rf][db][rr]: q = l15 (col), d = db*16+lg*4+rr (row)

  const uint8_t* KpB = (const uint8_t*)Kp + ((size_t)b * N_ * KVD_ + (size_t)hkv * HD_) * 2;
  const uint8_t* VtB = (const uint8_t*)Vt + (size_t)(b * HKV_ + hkv) * HD_ * (size_t)N_ * 2;
  uint8_t* PwB = (uint8_t*)Ps[wave];

  const int Tw   = qtile / 2 + 1;     // this wave's causal tile count
  const int Tmax = 2 * bx + 2;        // block's tile count

  auto stage = [&](int buf, int t) {
    uint8_t* KsB = (uint8_t*)Ks[buf];
    uint8_t* VsB = (uint8_t*)Vs[buf];
#pragma unroll
    for (int r = 0; r < 4; ++r) {
      int o16 = r * 4096 + wave * 1024 + lane * 16;
      int row = o16 >> 8;
      int colB = (o16 & 255) ^ ((row & 7) << 4);
      ld_g2l(KsB + r * 4096 + wave * 1024,
             KpB + (size_t)(t * 64 + row) * (KVD_ * 2) + colB);
    }
#pragma unroll
    for (int r = 0; r < 4; ++r) {
      int o16 = r * 4096 + wave * 1024 + lane * 16;
      int dd = o16 >> 7;
      int colB = (o16 & 127) ^ ((dd & 7) << 4);
      ld_g2l(VsB + r * 4096 + wave * 1024,
             VtB + (size_t)dd * (N_ * 2) + t * 128 + colB);
    }
  };

  stage(0, 0);
  __syncthreads();
  int cur = 0;

  for (int t = 0; t < Tmax; ++t) {
    if (t + 1 < Tmax) stage(cur ^ 1, t + 1);   // prefetch next tile (async)

    if (t < Tw) {
      const uint8_t* KsB = (const uint8_t*)Ks[cur];
      const uint8_t* VsB = (const uint8_t*)Vs[cur];

      // S^T = K Q^T : s4[rf][kb], lane holds [key = kb*16+lg*4+rr][q = l15]
      f32x4 s4[2][4] = {};
      __builtin_amdgcn_s_setprio(1);
#pragma unroll
      for (int ks = 0; ks < 4; ++ks) {
        int koff = ks * 64 + lg * 16;
#pragma unroll
        for (int kb = 0; kb < 4; ++kb) {
          int row = kb * 16 + l15;
          bf16x8 kf = *(const bf16x8*)(KsB + row * 256 + (koff ^ ((row & 7) << 4)));
          s4[0][kb] = __builtin_amdgcn_mfma_f32_16x16x32_bf16(kf, qf[0][ks], s4[0][kb], 0, 0, 0);
          s4[1][kb] = __builtin_amdgcn_mfma_f32_16x16x32_bf16(kf, qf[1][ks], s4[1][kb], 0, 0, 0);
        }
      }
      __builtin_amdgcn_s_setprio(0);

      // causal mask on this wave's last tile: key > query -> -inf
      if (t == Tw - 1) {
#pragma unroll
        for (int rf = 0; rf < 2; ++rf) {
          int q = qtile * 32 + rf * 16 + l15;
#pragma unroll
          for (int kb = 0; kb < 4; ++kb) {
            int key = t * 64 + kb * 16 + lg * 4;
#pragma unroll
            for (int rr = 0; rr < 4; ++rr)
              if (key + rr > q) s4[rf][kb][rr] = -1e30f;
          }
        }
      }

      // lane-local online softmax + P round-trip (pf kept in regs)
      bf16x8 pf[2][2];
#pragma unroll
      for (int rf = 0; rf < 2; ++rf) {
        f32x4 mx = vmax4(vmax4(s4[rf][0], s4[rf][1]), vmax4(s4[rf][2], s4[rf][3]));
        float rm = fmaxf(fmaxf(mx[0], mx[1]), fmaxf(mx[2], mx[3]));
        rm = fmaxf(rm, __shfl_xor(rm, 16));
        rm = fmaxf(rm, __shfl_xor(rm, 32));
        float mn = fmaxf(m[rf], rm);
        float sc = __expf(m[rf] - mn);

        f32x4 p[4];
        f32x4 psum = {0.f, 0.f, 0.f, 0.f};
#pragma unroll
        for (int kb = 0; kb < 4; ++kb) {
#pragma unroll
          for (int rr = 0; rr < 4; ++rr)
            p[kb][rr] = __expf(s4[rf][kb][rr] - mn);
          psum += p[kb];
        }
        float rs = (psum[0] + psum[1]) + (psum[2] + psum[3]);
        rs += __shfl_xor(rs, 16);
        rs += __shfl_xor(rs, 32);
        ln[rf] = ln[rf] * sc + rs;
        m[rf] = mn;

#pragma unroll
        for (int db = 0; db < 8; ++db) o[rf][db] *= sc;

        // P -> per-wave LDS row q=l15 (4 packed 8B stores), then pf reads
#pragma unroll
        for (int kb = 0; kb < 4; ++kb) {
          union { bf16_t h[4]; uint2 u; } pk;
          pk.h[0] = (bf16_t)p[kb][0]; pk.h[1] = (bf16_t)p[kb][1];
          pk.h[2] = (bf16_t)p[kb][2]; pk.h[3] = (bf16_t)p[kb][3];
          *(uint2*)(PwB + l15 * 144 + kb * 32 + lg * 8) = pk.u;
        }
        pf[rf][0] = *(const bf16x8*)(PwB + l15 * 144 + lg * 16);
        pf[rf][1] = *(const bf16x8*)(PwB + l15 * 144 + 64 + lg * 16);
      }

      // O^T += V^T P^T : vf rows = d (shared by both rf)
      __builtin_amdgcn_s_setprio(1);
#pragma unroll
      for (int ks2 = 0; ks2 < 2; ++ks2) {
        int koff = ks2 * 64 + lg * 16;
#pragma unroll
        for (int db = 0; db < 8; ++db) {
          int dd = db * 16 + l15;
          bf16x8 vf = *(const bf16x8*)(VsB + dd * 128 + (koff ^ ((dd & 7) << 4)));
          o[0][db] = __builtin_amdgcn_mfma_f32_16x16x32_bf16(vf, pf[0][ks2], o[0][db], 0, 0, 0);
          o[1][db] = __builtin_amdgcn_mfma_f32_16x16x32_bf16(vf, pf[1][ks2], o[1][db], 0, 0, 0);
        }
      }
      __builtin_amdgcn_s_setprio(0);
    }

    __syncthreads();   // staged t+1 complete; all reads of buf[cur] done
    cur ^= 1;
  }

  // epilogue: lane q = l15; d = db*16 + lg*4 + rr -> packed 8B stores
#pragma unroll
  for (int rf = 0; rf < 2; ++rf) {
    float iv = 1.f / ln[rf];
    size_t qrow = (size_t)b * N_ + qtile * 32 + rf * 16 + l15;
    uint8_t* ob = (uint8_t*)(AO + qrow * DIM_ + (size_t)hq * HD_);
#pragma unroll
    for (int db = 0; db < 8; ++db) {
      union { bf16_t h[4]; uint2 u; } pk;
      pk.h[0] = (bf16_t)(o[rf][db][0] * iv);
      pk.h[1] = (bf16_t)(o[rf][db][1] * iv);
      pk.h[2] = (bf16_t)(o[rf][db][2] * iv);
      pk.h[3] = (bf16_t)(o[rf][db][3] * iv);
      *(uint2*)(ob + (db * 16 + lg * 4) * 2) = pk.u;
    }
  }
}

// ---------------------------------------------------------------------------
extern "C" void kernel_launch(void* const* d_in, const int* in_sizes, int n_in,
                              void* d_out, int out_size, void* d_ws, size_t ws_size,
                              hipStream_t stream)
{
  if (ws_size < (46u << 20)) return;  // proven sufficient in rounds 3-12

  const float* query = (const float*)d_in[0];
  const float* key   = (const float*)d_in[1];
  const float* value = (const float*)d_in[2];
  const float* Wq = (const float*)d_in[3];
  const float* bq = (const float*)d_in[4];
  const float* Wk = (const float*)d_in[5];
  const float* bk = (const float*)d_in[6];
  const float* Wv = (const float*)d_in[7];
  const float* bv = (const float*)d_in[8];
  const float* Wo = (const float*)d_in[9];
  const float* bo = (const float*)d_in[10];
  float* out = (float*)d_out;

  uint8_t* ws = (uint8_t*)d_ws;
  float*  cosT = (float*)(ws);                       // 0.5 MB
  float*  sinT = (float*)(ws + (512u << 10));        // 0.5 MB
  bf16_t* Qp   = (bf16_t*)(ws + (1u  << 20));        // 16 MB [4096][2048] (+ attn out)
  bf16_t* Kp   = (bf16_t*)(ws + (17u << 20));        // 4 MB  [4096][512]
  bf16_t* Vp   = (bf16_t*)(ws + (21u << 20));        // 4 MB  [4096][512]
  bf16_t* Vt   = (bf16_t*)(ws + (25u << 20));        // 4 MB  [8][128][2048]
  bf16_t* Wqb  = (bf16_t*)(ws + (29u << 20));        // 8 MB  [2048][2048]
  bf16_t* Wkb  = (bf16_t*)(ws + (37u << 20));        // 2 MB  [512][2048]
  bf16_t* Wvb  = (bf16_t*)(ws + (39u << 20));        // 2 MB  [512][2048]
  bf16_t* Wob  = (bf16_t*)(ws + (17u << 20));        // 8 MB, post-attn over Kp+Vp

  k_sincos<<<512, 256, 0, stream>>>(cosT, sinT);

  // convert Wq/Wk/Wv to bf16 (6.3M elems, one fused launch)
  k_cvt3<<<6144, 256, 0, stream>>>(Wq, Wqb, 4194304,
                                   Wk, Wkb, 1048576,
                                   Wv, Wvb, 1048576);

  // Q+K+V projections in one launch, 64x128 tiles BK=128 (z=0 Q, z=1 K, z=2 V)
  k_gemm_qkv<<<dim3(64, 16, 3), 256, 0, stream>>>(
      query, Wqb, bq, Qp, key, Wkb, bk, Kp, value, Wvb, bv, Vp);

  // vectorized RoPE: Q = 4096*16*8 threads, K = 4096*4*8 threads
  k_rope<<<2048, 256, 0, stream>>>(Qp, cosT, sinT, 4, SCALE_);
  k_rope<<<512,  256, 0, stream>>>(Kp, cosT, sinT, 2, 1.0f);

  k_transpose_v<<<dim3(64, 8), 256, 0, stream>>>(Vp, Vt);

  // flash attention: LPT order + double-buffered staging, in-place output
  k_attn<<<dim3(16, 32), 256, 0, stream>>>(Qp, Kp, Vt, Qp);

  // convert Wo (after attn; reuses dead Kp/Vp space)
  k_cvt3<<<4096, 256, 0, stream>>>(Wo, Wob, 4194304,
                                   nullptr, nullptr, 0,
                                   nullptr, nullptr, 0);

  // Output projection: M=4096 N=2048 K=2048, BK=128 (A bf16 g2l, C f32)
  k_gemm_o<<<dim3(64, 16), 256, 0, stream>>>(Qp, Wob, bo, out);
}

// Round 14
// 249.197 us; speedup vs baseline: 1.0345x; 1.0345x over previous
//
#include <hip/hip_runtime.h>
#include <cstdint>

// ---------------------------------------------------------------------------
// GroupedQueryAttention: B=2 N=2048 DIM=2048 HQ=16 HKV=4 HD=128, causal, RoPE.
// f32 I/O, bf16 internals. Round 14:
//  - GEMMs: reverted to r10 geometry (128x128, BK=64, lb(256,4)).
//  - NEW: if ws >= 90MB, pre-convert q/k/v to bf16 and run QKV fully via
//    global_load_lds (the proven O-proj path, ~764 TF vs 495 TF for f32-A).
//    Else: exact r10 behavior (proven 235us). Graduated, risk-free probe.
//  - attention / rope / transpose unchanged.
// ---------------------------------------------------------------------------

typedef __bf16 bf16_t;
typedef __attribute__((ext_vector_type(8))) __bf16 bf16x8;
typedef __attribute__((ext_vector_type(4))) float f32x4;

#define B_    2
#define N_    2048
#define DIM_  2048
#define HQ_   16
#define HKV_  4
#define HD_   128
#define KVD_  512
#define SCALE_ 0.08838834764831845f  // 128^-0.5

// async global->LDS, 16B per lane. lds dest must be wave-uniform base.
static __device__ __forceinline__ void ld_g2l(void* lds, const void* g) {
  __builtin_amdgcn_global_load_lds((__attribute__((address_space(1))) void*)g,
                                   (__attribute__((address_space(3))) void*)lds,
                                   16, 0, 0);
}

static __device__ __forceinline__ f32x4 vmax4(f32x4 a, f32x4 b) {
  f32x4 r;
  r[0] = fmaxf(a[0], b[0]); r[1] = fmaxf(a[1], b[1]);
  r[2] = fmaxf(a[2], b[2]); r[3] = fmaxf(a[3], b[3]);
  return r;
}

// ---------------------------------------------------------------------------
// cos/sin table: [2048][64] each, f32.  inv_freq = 10000^(-i/64) (base_adj==1)
// ---------------------------------------------------------------------------
__global__ void k_sincos(float* __restrict__ cosT, float* __restrict__ sinT) {
  int idx = blockIdx.x * 256 + threadIdx.x;  // 2048*64
  int i = idx & 63;
  int n = idx >> 6;
  float inv = expf(-(float)i * (9.210340371976184f / 64.0f));  // ln(1e4)/64
  float ang = (float)n * inv;
  cosT[idx] = cosf(ang);
  sinT[idx] = sinf(ang);
}

// ---------------------------------------------------------------------------
// fused f32 -> bf16 conversion for up to three tensors (4 elems/thread)
// ---------------------------------------------------------------------------
__global__ void k_cvt3(const float* __restrict__ s0, bf16_t* __restrict__ d0, int n0,
                       const float* __restrict__ s1, bf16_t* __restrict__ d1, int n1,
                       const float* __restrict__ s2, bf16_t* __restrict__ d2, int n2)
{
  int i = (blockIdx.x * 256 + threadIdx.x) * 4;
  const float* s; bf16_t* d; int off;
  if (i < n0)                { s = s0; d = d0; off = i; }
  else if (i < n0 + n1)      { s = s1; d = d1; off = i - n0; }
  else if (i < n0 + n1 + n2) { s = s2; d = d2; off = i - n0 - n1; }
  else return;
  f32x4 v = *(const f32x4*)(s + off);
  union { bf16_t h[4]; uint2 u; } pk;
  pk.h[0] = (bf16_t)v[0]; pk.h[1] = (bf16_t)v[1];
  pk.h[2] = (bf16_t)v[2]; pk.h[3] = (bf16_t)v[3];
  *(uint2*)(d + off) = pk.u;
}

// ---------------------------------------------------------------------------
// Shared GEMM body (r10): C = A @ W^T + bias.  A f32 reg-staged (AMODE=0) or
// bf16 g2l (AMODE=1); W bf16 g2l; C f32 or bf16. 128x128 tile, BK=64,
// 4 waves of 64x64. LDS [128][64] bf16, XOR swizzle byte^((row&7)<<4).
// ---------------------------------------------------------------------------
template <int AMODE, bool CF32>
static __device__ __forceinline__ void gemm_body(
    const void* __restrict__ Av, const bf16_t* __restrict__ W,
    const float* __restrict__ bias, void* __restrict__ Cv,
    int N, int K, int bm, int bn, bf16_t* As, bf16_t* Bs)
{
  const int tid  = threadIdx.x;
  const int lane = tid & 63;
  const int wave = tid >> 6;
  const int l15  = lane & 15;
  const int lg   = lane >> 4;
  const int wr = (wave >> 1) * 64, wc = (wave & 1) * 64;

  f32x4 acc[4][4] = {};

  uint8_t* AsB = (uint8_t*)As;
  uint8_t* BsB = (uint8_t*)Bs;
  const uint8_t* Wbase = (const uint8_t*)W + (size_t)(bn * 128) * K * 2;
  const uint8_t* AbaseB = (const uint8_t*)Av + (size_t)(bm * 128) * K * 2; // bf16 case

  for (int k0 = 0; k0 < K; k0 += 64) {
    // W tile: global_load_lds, LDS[row][cl] = G[row][cl ^ swz(row)]
    for (int r = 0; r < 4; ++r) {
      int o = r * 4096 + wave * 1024 + lane * 16;
      int row = o >> 7;
      int colB = (o & 127) ^ ((row & 7) << 4);
      ld_g2l(BsB + r * 4096 + wave * 1024,
             Wbase + (size_t)row * (K * 2) + (size_t)k0 * 2 + colB);
    }
    // A tile
    if (AMODE == 1) {
      for (int r = 0; r < 4; ++r) {
        int o = r * 4096 + wave * 1024 + lane * 16;
        int row = o >> 7;
        int colB = (o & 127) ^ ((row & 7) << 4);
        ld_g2l(AsB + r * 4096 + wave * 1024,
               AbaseB + (size_t)row * (K * 2) + (size_t)k0 * 2 + colB);
      }
    } else {
      for (int i = 0; i < 4; ++i) {
        int c = i * 256 + tid;
        int row = c >> 3;            // 0..127
        int k8  = (c & 7) * 8;       // element offset within K-tile
        const float* ap = (const float*)Av + (size_t)(bm * 128 + row) * K + k0 + k8;
        f32x4 alo = *(const f32x4*)ap;
        f32x4 ahi = *(const f32x4*)(ap + 4);
        bf16x8 va;
        va[0] = (bf16_t)alo[0]; va[1] = (bf16_t)alo[1];
        va[2] = (bf16_t)alo[2]; va[3] = (bf16_t)alo[3];
        va[4] = (bf16_t)ahi[0]; va[5] = (bf16_t)ahi[1];
        va[6] = (bf16_t)ahi[2]; va[7] = (bf16_t)ahi[3];
        int sw = (k8 * 2) ^ ((row & 7) << 4);
        *(bf16x8*)(AsB + row * 128 + sw) = va;
      }
    }
    __syncthreads();
    for (int kk = 0; kk < 2; ++kk) {
      const int koff = kk * 64 + (lg << 4);
      bf16x8 fa[4], fb[4];
      for (int fi = 0; fi < 4; ++fi) {
        int row = wr + fi * 16 + l15;
        fa[fi] = *(const bf16x8*)(AsB + row * 128 + (koff ^ ((row & 7) << 4)));
      }
      for (int fj = 0; fj < 4; ++fj) {
        int row = wc + fj * 16 + l15;
        fb[fj] = *(const bf16x8*)(BsB + row * 128 + (koff ^ ((row & 7) << 4)));
      }
      for (int fi = 0; fi < 4; ++fi)
        for (int fj = 0; fj < 4; ++fj)
          acc[fi][fj] = __builtin_amdgcn_mfma_f32_16x16x32_bf16(
              fa[fi], fb[fj], acc[fi][fj], 0, 0, 0);
    }
    __syncthreads();
  }

  // epilogue: C/D layout col=lane&15, row=(lane>>4)*4+r
  const int r0 = lg * 4;
  for (int fi = 0; fi < 4; ++fi) {
    for (int rr = 0; rr < 4; ++rr) {
      int grow = bm * 128 + wr + fi * 16 + r0 + rr;
      size_t rowoff = (size_t)grow * N;
      for (int fj = 0; fj < 4; ++fj) {
        int gcol = bn * 128 + wc + fj * 16 + l15;
        float v = acc[fi][fj][rr] + bias[gcol];
        if (CF32) ((float*)Cv)[rowoff + gcol] = v;
        else      ((bf16_t*)Cv)[rowoff + gcol] = (bf16_t)v;
      }
    }
  }
}

// QKV projections, A = f32 (r10 path): z=0 Q (N=2048), z=1 K, z=2 V
__global__ __launch_bounds__(256, 4) void k_gemm_qkv(
    const float* __restrict__ q, const bf16_t* __restrict__ Wqb,
    const float* __restrict__ bq, bf16_t* __restrict__ Qp,
    const float* __restrict__ k, const bf16_t* __restrict__ Wkb,
    const float* __restrict__ bk, bf16_t* __restrict__ Kp,
    const float* __restrict__ v, const bf16_t* __restrict__ Wvb,
    const float* __restrict__ bv, bf16_t* __restrict__ Vp)
{
  __shared__ bf16_t As[128 * 64];
  __shared__ bf16_t Bs[128 * 64];
  const int z = blockIdx.z;
  if (z != 0 && blockIdx.y >= 4) return;
  const float* A; const bf16_t* W; const float* bias; bf16_t* C; int Nn;
  if (z == 0)      { A = q; W = Wqb; bias = bq; C = Qp; Nn = 2048; }
  else if (z == 1) { A = k; W = Wkb; bias = bk; C = Kp; Nn = 512; }
  else             { A = v; W = Wvb; bias = bv; C = Vp; Nn = 512; }
  gemm_body<0, false>(A, W, bias, C, Nn, 2048, blockIdx.x, blockIdx.y, As, Bs);
}

// QKV projections, A = bf16 pre-converted (large-ws path): full g2l
__global__ __launch_bounds__(256, 4) void k_gemm_qkv16(
    const bf16_t* __restrict__ q, const bf16_t* __restrict__ Wqb,
    const float* __restrict__ bq, bf16_t* __restrict__ Qp,
    const bf16_t* __restrict__ k, const bf16_t* __restrict__ Wkb,
    const float* __restrict__ bk, bf16_t* __restrict__ Kp,
    const bf16_t* __restrict__ v, const bf16_t* __restrict__ Wvb,
    const float* __restrict__ bv, bf16_t* __restrict__ Vp)
{
  __shared__ bf16_t As[128 * 64];
  __shared__ bf16_t Bs[128 * 64];
  const int z = blockIdx.z;
  if (z != 0 && blockIdx.y >= 4) return;
  const bf16_t* A; const bf16_t* W; const float* bias; bf16_t* C; int Nn;
  if (z == 0)      { A = q; W = Wqb; bias = bq; C = Qp; Nn = 2048; }
  else if (z == 1) { A = k; W = Wkb; bias = bk; C = Kp; Nn = 512; }
  else             { A = v; W = Wvb; bias = bv; C = Vp; Nn = 512; }
  gemm_body<1, false>(A, W, bias, C, Nn, 2048, blockIdx.x, blockIdx.y, As, Bs);
}

// O projection: A bf16 g2l, C f32
__global__ __launch_bounds__(256, 4) void k_gemm_o(
    const bf16_t* __restrict__ Ain, const bf16_t* __restrict__ Wob,
    const float* __restrict__ bo, float* __restrict__ out)
{
  __shared__ bf16_t As[128 * 64];
  __shared__ bf16_t Bs[128 * 64];
  gemm_body<1, true>(Ain, Wob, bo, out, 2048, 2048, blockIdx.x, blockIdx.y, As, Bs);
}

// ---------------------------------------------------------------------------
// RoPE in-place on X:[4096][nheads*128] bf16, vectorized (8 pairs/thread).
// ---------------------------------------------------------------------------
__global__ void k_rope(bf16_t* __restrict__ X, const float* __restrict__ cosT,
                       const float* __restrict__ sinT, int lgnh, float outScale)
{
  int idx = blockIdx.x * 256 + threadIdx.x;
  int j = idx & 7;                       // d0 = j*8
  int h = (idx >> 3) & ((1 << lgnh) - 1);
  int row = idx >> (3 + lgnh);
  int n = row & (N_ - 1);
  int d0 = j * 8;
  const float* cp = cosT + (n << 6) + d0;
  const float* sp = sinT + (n << 6) + d0;
  f32x4 c0 = *(const f32x4*)cp,  c1 = *(const f32x4*)(cp + 4);
  f32x4 s0 = *(const f32x4*)sp,  s1 = *(const f32x4*)(sp + 4);
  bf16_t* xb = X + (size_t)row * (size_t)(128 << lgnh) + (h << 7) + d0;
  bf16x8 x1 = *(const bf16x8*)xb;
  bf16x8 x2 = *(const bf16x8*)(xb + 64);
  bf16x8 o1, o2;
#pragma unroll
  for (int e = 0; e < 8; ++e) {
    float c = e < 4 ? c0[e] : c1[e - 4];
    float s = e < 4 ? s0[e] : s1[e - 4];
    float a = (float)x1[e], bvl = (float)x2[e];
    o1[e] = (bf16_t)((a * c - bvl * s) * outScale);
    o2[e] = (bf16_t)((bvl * c + a * s) * outScale);
  }
  *(bf16x8*)xb = o1;
  *(bf16x8*)(xb + 64) = o2;
}

// ---------------------------------------------------------------------------
// Vp:[4096][512] -> Vt:[B*HKV][128][2048]  (Vt[bh][d][n] = Vp[b*2048+n][hkv*128+d])
// ---------------------------------------------------------------------------
__global__ void k_transpose_v(const bf16_t* __restrict__ Vp, bf16_t* __restrict__ Vt)
{
  __shared__ bf16_t tile[64][72];
  const int tid = threadIdx.x;
  const int r0 = blockIdx.x * 64;  // global row (b*2048+n)
  const int d0 = blockIdx.y * 64;  // col in [0,512)
  for (int r = 0; r < 2; ++r) {
    int n = r * 32 + (tid >> 3);
    int dc = (tid & 7) * 8;
    *(uint4*)&tile[n][dc] = *(const uint4*)(Vp + (size_t)(r0 + n) * KVD_ + d0 + dc);
  }
  __syncthreads();
  const int b = r0 >> 11;
  const int nseq = r0 & (N_ - 1);
  for (int r = 0; r < 2; ++r) {
    int dd = r * 32 + (tid >> 3);
    int nc = (tid & 7) * 8;
    int dglob = d0 + dd;
    int hkv = dglob >> 7, dloc = dglob & 127;
    union { bf16_t h[8]; uint4 v; } pk;
    for (int j = 0; j < 8; ++j) pk.h[j] = tile[nc + j][dd];
    size_t drow = (size_t)(b * HKV_ + hkv) * 128 + dloc;
    *(uint4*)(Vt + drow * N_ + nseq + nc) = pk.v;
  }
}

// ---------------------------------------------------------------------------
// Flash attention, causal GQA (r9 structure): LPT order, dbuf K/V staging,
// swapped-operand lane-local softmax, setprio, output in-place into Qp.
// ---------------------------------------------------------------------------
__global__ __launch_bounds__(256, 2) void k_attn(
    const bf16_t* __restrict__ Qp, const bf16_t* __restrict__ Kp,
    const bf16_t* __restrict__ Vt, bf16_t* __restrict__ AO)
{
  __shared__ bf16_t Ks[2][64 * 128];
  __shared__ bf16_t Vs[2][128 * 64];
  __shared__ bf16_t Ps[4][16 * 72];
  const int tid = threadIdx.x, lane = tid & 63, wave = tid >> 6;
  const int l15 = lane & 15, lg = lane >> 4;
  const int bx = 15 - (int)blockIdx.x;       // LPT: heavy blocks dispatch first
  const int qtile = bx * 4 + wave;
  const int bh = blockIdx.y;
  const int b = bh >> 4, hq = bh & 15, hkv = hq >> 2;

  // Q fragments: 2 row-frags x 4 k-steps (RoPE'd, scale folded)
  bf16x8 qf[2][4];
  for (int rf = 0; rf < 2; ++rf) {
    size_t qrow = (size_t)b * N_ + qtile * 32 + rf * 16 + l15;
    const uint8_t* qb = (const uint8_t*)Qp + (qrow * DIM_ + (size_t)hq * HD_) * 2 + lg * 16;
    for (int ks = 0; ks < 4; ++ks)
      qf[rf][ks] = *(const bf16x8*)(qb + ks * 64);
  }

  float m[2] = {-1e30f, -1e30f};
  float ln[2] = {0.f, 0.f};
  f32x4 o[2][8] = {};   // o[rf][db][rr]: q = l15 (col), d = db*16+lg*4+rr (row)

  const uint8_t* KpB = (const uint8_t*)Kp + ((size_t)b * N_ * KVD_ + (size_t)hkv * HD_) * 2;
  const uint8_t* VtB = (const uint8_t*)Vt + (size_t)(b * HKV_ + hkv) * HD_ * (size_t)N_ * 2;
  uint8_t* PwB = (uint8_t*)Ps[wave];

  const int Tw   = qtile / 2 + 1;     // this wave's causal tile count
  const int Tmax = 2 * bx + 2;        // block's tile count

  auto stage = [&](int buf, int t) {
    uint8_t* KsB = (uint8_t*)Ks[buf];
    uint8_t* VsB = (uint8_t*)Vs[buf];
#pragma unroll
    for (int r = 0; r < 4; ++r) {
      int o16 = r * 4096 + wave * 1024 + lane * 16;
      int row = o16 >> 8;
      int colB = (o16 & 255) ^ ((row & 7) << 4);
      ld_g2l(KsB + r * 4096 + wave * 1024,
             KpB + (size_t)(t * 64 + row) * (KVD_ * 2) + colB);
    }
#pragma unroll
    for (int r = 0; r < 4; ++r) {
      int o16 = r * 4096 + wave * 1024 + lane * 16;
      int dd = o16 >> 7;
      int colB = (o16 & 127) ^ ((dd & 7) << 4);
      ld_g2l(VsB + r * 4096 + wave * 1024,
             VtB + (size_t)dd * (N_ * 2) + t * 128 + colB);
    }
  };

  stage(0, 0);
  __syncthreads();
  int cur = 0;

  for (int t = 0; t < Tmax; ++t) {
    if (t + 1 < Tmax) stage(cur ^ 1, t + 1);   // prefetch next tile (async)

    if (t < Tw) {
      const uint8_t* KsB = (const uint8_t*)Ks[cur];
      const uint8_t* VsB = (const uint8_t*)Vs[cur];

      // S^T = K Q^T : s4[rf][kb], lane holds [key = kb*16+lg*4+rr][q = l15]
      f32x4 s4[2][4] = {};
      __builtin_amdgcn_s_setprio(1);
#pragma unroll
      for (int ks = 0; ks < 4; ++ks) {
        int koff = ks * 64 + lg * 16;
#pragma unroll
        for (int kb = 0; kb < 4; ++kb) {
          int row = kb * 16 + l15;
          bf16x8 kf = *(const bf16x8*)(KsB + row * 256 + (koff ^ ((row & 7) << 4)));
          s4[0][kb] = __builtin_amdgcn_mfma_f32_16x16x32_bf16(kf, qf[0][ks], s4[0][kb], 0, 0, 0);
          s4[1][kb] = __builtin_amdgcn_mfma_f32_16x16x32_bf16(kf, qf[1][ks], s4[1][kb], 0, 0, 0);
        }
      }
      __builtin_amdgcn_s_setprio(0);

      // causal mask on this wave's last tile: key > query -> -inf
      if (t == Tw - 1) {
#pragma unroll
        for (int rf = 0; rf < 2; ++rf) {
          int q = qtile * 32 + rf * 16 + l15;
#pragma unroll
          for (int kb = 0; kb < 4; ++kb) {
            int key = t * 64 + kb * 16 + lg * 4;
#pragma unroll
            for (int rr = 0; rr < 4; ++rr)
              if (key + rr > q) s4[rf][kb][rr] = -1e30f;
          }
        }
      }

      // lane-local online softmax + P round-trip (pf kept in regs)
      bf16x8 pf[2][2];
#pragma unroll
      for (int rf = 0; rf < 2; ++rf) {
        f32x4 mx = vmax4(vmax4(s4[rf][0], s4[rf][1]), vmax4(s4[rf][2], s4[rf][3]));
        float rm = fmaxf(fmaxf(mx[0], mx[1]), fmaxf(mx[2], mx[3]));
        rm = fmaxf(rm, __shfl_xor(rm, 16));
        rm = fmaxf(rm, __shfl_xor(rm, 32));
        float mn = fmaxf(m[rf], rm);
        float sc = __expf(m[rf] - mn);

        f32x4 p[4];
        f32x4 psum = {0.f, 0.f, 0.f, 0.f};
#pragma unroll
        for (int kb = 0; kb < 4; ++kb) {
#pragma unroll
          for (int rr = 0; rr < 4; ++rr)
            p[kb][rr] = __expf(s4[rf][kb][rr] - mn);
          psum += p[kb];
        }
        float rs = (psum[0] + psum[1]) + (psum[2] + psum[3]);
        rs += __shfl_xor(rs, 16);
        rs += __shfl_xor(rs, 32);
        ln[rf] = ln[rf] * sc + rs;
        m[rf] = mn;

#pragma unroll
        for (int db = 0; db < 8; ++db) o[rf][db] *= sc;

        // P -> per-wave LDS row q=l15 (4 packed 8B stores), then pf reads
#pragma unroll
        for (int kb = 0; kb < 4; ++kb) {
          union { bf16_t h[4]; uint2 u; } pk;
          pk.h[0] = (bf16_t)p[kb][0]; pk.h[1] = (bf16_t)p[kb][1];
          pk.h[2] = (bf16_t)p[kb][2]; pk.h[3] = (bf16_t)p[kb][3];
          *(uint2*)(PwB + l15 * 144 + kb * 32 + lg * 8) = pk.u;
        }
        pf[rf][0] = *(const bf16x8*)(PwB + l15 * 144 + lg * 16);
        pf[rf][1] = *(const bf16x8*)(PwB + l15 * 144 + 64 + lg * 16);
      }

      // O^T += V^T P^T : vf rows = d (shared by both rf)
      __builtin_amdgcn_s_setprio(1);
#pragma unroll
      for (int ks2 = 0; ks2 < 2; ++ks2) {
        int koff = ks2 * 64 + lg * 16;
#pragma unroll
        for (int db = 0; db < 8; ++db) {
          int dd = db * 16 + l15;
          bf16x8 vf = *(const bf16x8*)(VsB + dd * 128 + (koff ^ ((dd & 7) << 4)));
          o[0][db] = __builtin_amdgcn_mfma_f32_16x16x32_bf16(vf, pf[0][ks2], o[0][db], 0, 0, 0);
          o[1][db] = __builtin_amdgcn_mfma_f32_16x16x32_bf16(vf, pf[1][ks2], o[1][db], 0, 0, 0);
        }
      }
      __builtin_amdgcn_s_setprio(0);
    }

    __syncthreads();   // staged t+1 complete; all reads of buf[cur] done
    cur ^= 1;
  }

  // epilogue: lane q = l15; d = db*16 + lg*4 + rr -> packed 8B stores
#pragma unroll
  for (int rf = 0; rf < 2; ++rf) {
    float iv = 1.f / ln[rf];
    size_t qrow = (size_t)b * N_ + qtile * 32 + rf * 16 + l15;
    uint8_t* ob = (uint8_t*)(AO + qrow * DIM_ + (size_t)hq * HD_);
#pragma unroll
    for (int db = 0; db < 8; ++db) {
      union { bf16_t h[4]; uint2 u; } pk;
      pk.h[0] = (bf16_t)(o[rf][db][0] * iv);
      pk.h[1] = (bf16_t)(o[rf][db][1] * iv);
      pk.h[2] = (bf16_t)(o[rf][db][2] * iv);
      pk.h[3] = (bf16_t)(o[rf][db][3] * iv);
      *(uint2*)(ob + (db * 16 + lg * 4) * 2) = pk.u;
    }
  }
}

// ---------------------------------------------------------------------------
extern "C" void kernel_launch(void* const* d_in, const int* in_sizes, int n_in,
                              void* d_out, int out_size, void* d_ws, size_t ws_size,
                              hipStream_t stream)
{
  if (ws_size < (46u << 20)) return;  // proven sufficient in rounds 3-13

  const float* query = (const float*)d_in[0];
  const float* key   = (const float*)d_in[1];
  const float* value = (const float*)d_in[2];
  const float* Wq = (const float*)d_in[3];
  const float* bq = (const float*)d_in[4];
  const float* Wk = (const float*)d_in[5];
  const float* bk = (const float*)d_in[6];
  const float* Wv = (const float*)d_in[7];
  const float* bv = (const float*)d_in[8];
  const float* Wo = (const float*)d_in[9];
  const float* bo = (const float*)d_in[10];
  float* out = (float*)d_out;

  uint8_t* ws = (uint8_t*)d_ws;
  float*  cosT = (float*)(ws);                       // 0.5 MB
  float*  sinT = (float*)(ws + (512u << 10));        // 0.5 MB
  bf16_t* Qp   = (bf16_t*)(ws + (1u  << 20));        // 16 MB [4096][2048] (+ attn out)
  bf16_t* Kp   = (bf16_t*)(ws + (17u << 20));        // 4 MB  [4096][512]
  bf16_t* Vp   = (bf16_t*)(ws + (21u << 20));        // 4 MB  [4096][512]
  bf16_t* Vt   = (bf16_t*)(ws + (25u << 20));        // 4 MB  [8][128][2048]
  bf16_t* Wqb  = (bf16_t*)(ws + (29u << 20));        // 8 MB  [2048][2048]
  bf16_t* Wkb  = (bf16_t*)(ws + (37u << 20));        // 2 MB  [512][2048]
  bf16_t* Wvb  = (bf16_t*)(ws + (39u << 20));        // 2 MB  [512][2048]
  bf16_t* Wob  = (bf16_t*)(ws + (17u << 20));        // 8 MB, post-attn over Kp+Vp
  // large-ws branch only:
  bf16_t* qb16 = (bf16_t*)(ws + (41u << 20));        // 16 MB
  bf16_t* kb16 = (bf16_t*)(ws + (57u << 20));        // 16 MB
  bf16_t* vb16 = (bf16_t*)(ws + (73u << 20));        // 16 MB (end: 89 MB)

  const bool bigws = ws_size >= (90ull << 20);

  k_sincos<<<512, 256, 0, stream>>>(cosT, sinT);

  // convert Wq/Wk/Wv to bf16 (6.3M elems, one fused launch)
  k_cvt3<<<6144, 256, 0, stream>>>(Wq, Wqb, 4194304,
                                   Wk, Wkb, 1048576,
                                   Wv, Wvb, 1048576);

  if (bigws) {
    // pre-convert activations (25.2M elems) and run fully-g2l QKV
    k_cvt3<<<24576, 256, 0, stream>>>(query, qb16, 8388608,
                                      key,   kb16, 8388608,
                                      value, vb16, 8388608);
    k_gemm_qkv16<<<dim3(32, 16, 3), 256, 0, stream>>>(
        qb16, Wqb, bq, Qp, kb16, Wkb, bk, Kp, vb16, Wvb, bv, Vp);
  } else {
    // r10 path: A = f32 reg-staged
    k_gemm_qkv<<<dim3(32, 16, 3), 256, 0, stream>>>(
        query, Wqb, bq, Qp, key, Wkb, bk, Kp, value, Wvb, bv, Vp);
  }

  // vectorized RoPE: Q = 4096*16*8 threads, K = 4096*4*8 threads
  k_rope<<<2048, 256, 0, stream>>>(Qp, cosT, sinT, 4, SCALE_);
  k_rope<<<512,  256, 0, stream>>>(Kp, cosT, sinT, 2, 1.0f);

  k_transpose_v<<<dim3(64, 8), 256, 0, stream>>>(Vp, Vt);

  // flash attention: LPT order + double-buffered staging, in-place output
  k_attn<<<dim3(16, 32), 256, 0, stream>>>(Qp, Kp, Vt, Qp);

  // convert Wo (after attn; reuses dead Kp/Vp space)
  k_cvt3<<<4096, 256, 0, stream>>>(Wo, Wob, 4194304,
                                   nullptr, nullptr, 0,
                                   nullptr, nullptr, 0);

  // Output projection: M=4096 N=2048 K=2048 (A bf16 g2l, W bf16 g2l, C f32)
  k_gemm_o<<<dim3(32, 16), 256, 0, stream>>>(Qp, Wob, bo, out);
}

// Round 15
// 218.099 us; speedup vs baseline: 1.1821x; 1.1426x over previous
//
#include <hip/hip_runtime.h>
#include <cstdint>

// ---------------------------------------------------------------------------
// GroupedQueryAttention: B=2 N=2048 DIM=2048 HQ=16 HKV=4 HD=128, causal, RoPE.
// f32 I/O, bf16 internals. Round 15:
//  - attention: complementary block pairing (y<16 ? 15-x : x) so each CU's
//    two resident blocks sum to exactly 34 tiles (was same-x pairing -> 64);
//    + defer-max (T13, wave-uniform) skipping o-rescale on stable tiles.
//  - QKV reverted to r10 f32-A path (r14 A/B: cvt-act costs more than it saves).
//  - everything else unchanged from r10.
// ---------------------------------------------------------------------------

typedef __bf16 bf16_t;
typedef __attribute__((ext_vector_type(8))) __bf16 bf16x8;
typedef __attribute__((ext_vector_type(4))) float f32x4;

#define B_    2
#define N_    2048
#define DIM_  2048
#define HQ_   16
#define HKV_  4
#define HD_   128
#define KVD_  512
#define SCALE_ 0.08838834764831845f  // 128^-0.5

// async global->LDS, 16B per lane. lds dest must be wave-uniform base.
static __device__ __forceinline__ void ld_g2l(void* lds, const void* g) {
  __builtin_amdgcn_global_load_lds((__attribute__((address_space(1))) void*)g,
                                   (__attribute__((address_space(3))) void*)lds,
                                   16, 0, 0);
}

static __device__ __forceinline__ f32x4 vmax4(f32x4 a, f32x4 b) {
  f32x4 r;
  r[0] = fmaxf(a[0], b[0]); r[1] = fmaxf(a[1], b[1]);
  r[2] = fmaxf(a[2], b[2]); r[3] = fmaxf(a[3], b[3]);
  return r;
}

// ---------------------------------------------------------------------------
// cos/sin table: [2048][64] each, f32.  inv_freq = 10000^(-i/64) (base_adj==1)
// ---------------------------------------------------------------------------
__global__ void k_sincos(float* __restrict__ cosT, float* __restrict__ sinT) {
  int idx = blockIdx.x * 256 + threadIdx.x;  // 2048*64
  int i = idx & 63;
  int n = idx >> 6;
  float inv = expf(-(float)i * (9.210340371976184f / 64.0f));  // ln(1e4)/64
  float ang = (float)n * inv;
  cosT[idx] = cosf(ang);
  sinT[idx] = sinf(ang);
}

// ---------------------------------------------------------------------------
// fused f32 -> bf16 conversion for up to three tensors (4 elems/thread)
// ---------------------------------------------------------------------------
__global__ void k_cvt3(const float* __restrict__ s0, bf16_t* __restrict__ d0, int n0,
                       const float* __restrict__ s1, bf16_t* __restrict__ d1, int n1,
                       const float* __restrict__ s2, bf16_t* __restrict__ d2, int n2)
{
  int i = (blockIdx.x * 256 + threadIdx.x) * 4;
  const float* s; bf16_t* d; int off;
  if (i < n0)                { s = s0; d = d0; off = i; }
  else if (i < n0 + n1)      { s = s1; d = d1; off = i - n0; }
  else if (i < n0 + n1 + n2) { s = s2; d = d2; off = i - n0 - n1; }
  else return;
  f32x4 v = *(const f32x4*)(s + off);
  union { bf16_t h[4]; uint2 u; } pk;
  pk.h[0] = (bf16_t)v[0]; pk.h[1] = (bf16_t)v[1];
  pk.h[2] = (bf16_t)v[2]; pk.h[3] = (bf16_t)v[3];
  *(uint2*)(d + off) = pk.u;
}

// ---------------------------------------------------------------------------
// Shared GEMM body (r10): C = A @ W^T + bias.  A f32 reg-staged (AMODE=0) or
// bf16 g2l (AMODE=1); W bf16 g2l; C f32 or bf16. 128x128 tile, BK=64,
// 4 waves of 64x64. LDS [128][64] bf16, XOR swizzle byte^((row&7)<<4).
// ---------------------------------------------------------------------------
template <int AMODE, bool CF32>
static __device__ __forceinline__ void gemm_body(
    const void* __restrict__ Av, const bf16_t* __restrict__ W,
    const float* __restrict__ bias, void* __restrict__ Cv,
    int N, int K, int bm, int bn, bf16_t* As, bf16_t* Bs)
{
  const int tid  = threadIdx.x;
  const int lane = tid & 63;
  const int wave = tid >> 6;
  const int l15  = lane & 15;
  const int lg   = lane >> 4;
  const int wr = (wave >> 1) * 64, wc = (wave & 1) * 64;

  f32x4 acc[4][4] = {};

  uint8_t* AsB = (uint8_t*)As;
  uint8_t* BsB = (uint8_t*)Bs;
  const uint8_t* Wbase = (const uint8_t*)W + (size_t)(bn * 128) * K * 2;
  const uint8_t* AbaseB = (const uint8_t*)Av + (size_t)(bm * 128) * K * 2; // bf16 case

  for (int k0 = 0; k0 < K; k0 += 64) {
    // W tile: global_load_lds, LDS[row][cl] = G[row][cl ^ swz(row)]
    for (int r = 0; r < 4; ++r) {
      int o = r * 4096 + wave * 1024 + lane * 16;
      int row = o >> 7;
      int colB = (o & 127) ^ ((row & 7) << 4);
      ld_g2l(BsB + r * 4096 + wave * 1024,
             Wbase + (size_t)row * (K * 2) + (size_t)k0 * 2 + colB);
    }
    // A tile
    if (AMODE == 1) {
      for (int r = 0; r < 4; ++r) {
        int o = r * 4096 + wave * 1024 + lane * 16;
        int row = o >> 7;
        int colB = (o & 127) ^ ((row & 7) << 4);
        ld_g2l(AsB + r * 4096 + wave * 1024,
               AbaseB + (size_t)row * (K * 2) + (size_t)k0 * 2 + colB);
      }
    } else {
      for (int i = 0; i < 4; ++i) {
        int c = i * 256 + tid;
        int row = c >> 3;            // 0..127
        int k8  = (c & 7) * 8;       // element offset within K-tile
        const float* ap = (const float*)Av + (size_t)(bm * 128 + row) * K + k0 + k8;
        f32x4 alo = *(const f32x4*)ap;
        f32x4 ahi = *(const f32x4*)(ap + 4);
        bf16x8 va;
        va[0] = (bf16_t)alo[0]; va[1] = (bf16_t)alo[1];
        va[2] = (bf16_t)alo[2]; va[3] = (bf16_t)alo[3];
        va[4] = (bf16_t)ahi[0]; va[5] = (bf16_t)ahi[1];
        va[6] = (bf16_t)ahi[2]; va[7] = (bf16_t)ahi[3];
        int sw = (k8 * 2) ^ ((row & 7) << 4);
        *(bf16x8*)(AsB + row * 128 + sw) = va;
      }
    }
    __syncthreads();
    for (int kk = 0; kk < 2; ++kk) {
      const int koff = kk * 64 + (lg << 4);
      bf16x8 fa[4], fb[4];
      for (int fi = 0; fi < 4; ++fi) {
        int row = wr + fi * 16 + l15;
        fa[fi] = *(const bf16x8*)(AsB + row * 128 + (koff ^ ((row & 7) << 4)));
      }
      for (int fj = 0; fj < 4; ++fj) {
        int row = wc + fj * 16 + l15;
        fb[fj] = *(const bf16x8*)(BsB + row * 128 + (koff ^ ((row & 7) << 4)));
      }
      for (int fi = 0; fi < 4; ++fi)
        for (int fj = 0; fj < 4; ++fj)
          acc[fi][fj] = __builtin_amdgcn_mfma_f32_16x16x32_bf16(
              fa[fi], fb[fj], acc[fi][fj], 0, 0, 0);
    }
    __syncthreads();
  }

  // epilogue: C/D layout col=lane&15, row=(lane>>4)*4+r
  const int r0 = lg * 4;
  for (int fi = 0; fi < 4; ++fi) {
    for (int rr = 0; rr < 4; ++rr) {
      int grow = bm * 128 + wr + fi * 16 + r0 + rr;
      size_t rowoff = (size_t)grow * N;
      for (int fj = 0; fj < 4; ++fj) {
        int gcol = bn * 128 + wc + fj * 16 + l15;
        float v = acc[fi][fj][rr] + bias[gcol];
        if (CF32) ((float*)Cv)[rowoff + gcol] = v;
        else      ((bf16_t*)Cv)[rowoff + gcol] = (bf16_t)v;
      }
    }
  }
}

// QKV projections in one launch: z=0 Q (N=2048), z=1 K, z=2 V (N=512, bn<4)
__global__ __launch_bounds__(256, 4) void k_gemm_qkv(
    const float* __restrict__ q, const bf16_t* __restrict__ Wqb,
    const float* __restrict__ bq, bf16_t* __restrict__ Qp,
    const float* __restrict__ k, const bf16_t* __restrict__ Wkb,
    const float* __restrict__ bk, bf16_t* __restrict__ Kp,
    const float* __restrict__ v, const bf16_t* __restrict__ Wvb,
    const float* __restrict__ bv, bf16_t* __restrict__ Vp)
{
  __shared__ bf16_t As[128 * 64];
  __shared__ bf16_t Bs[128 * 64];
  const int z = blockIdx.z;
  if (z != 0 && blockIdx.y >= 4) return;
  const float* A; const bf16_t* W; const float* bias; bf16_t* C; int Nn;
  if (z == 0)      { A = q; W = Wqb; bias = bq; C = Qp; Nn = 2048; }
  else if (z == 1) { A = k; W = Wkb; bias = bk; C = Kp; Nn = 512; }
  else             { A = v; W = Wvb; bias = bv; C = Vp; Nn = 512; }
  gemm_body<0, false>(A, W, bias, C, Nn, 2048, blockIdx.x, blockIdx.y, As, Bs);
}

// O projection: A bf16 g2l, C f32
__global__ __launch_bounds__(256, 4) void k_gemm_o(
    const bf16_t* __restrict__ Ain, const bf16_t* __restrict__ Wob,
    const float* __restrict__ bo, float* __restrict__ out)
{
  __shared__ bf16_t As[128 * 64];
  __shared__ bf16_t Bs[128 * 64];
  gemm_body<1, true>(Ain, Wob, bo, out, 2048, 2048, blockIdx.x, blockIdx.y, As, Bs);
}

// ---------------------------------------------------------------------------
// RoPE in-place on X:[4096][nheads*128] bf16, vectorized (8 pairs/thread).
// ---------------------------------------------------------------------------
__global__ void k_rope(bf16_t* __restrict__ X, const float* __restrict__ cosT,
                       const float* __restrict__ sinT, int lgnh, float outScale)
{
  int idx = blockIdx.x * 256 + threadIdx.x;
  int j = idx & 7;                       // d0 = j*8
  int h = (idx >> 3) & ((1 << lgnh) - 1);
  int row = idx >> (3 + lgnh);
  int n = row & (N_ - 1);
  int d0 = j * 8;
  const float* cp = cosT + (n << 6) + d0;
  const float* sp = sinT + (n << 6) + d0;
  f32x4 c0 = *(const f32x4*)cp,  c1 = *(const f32x4*)(cp + 4);
  f32x4 s0 = *(const f32x4*)sp,  s1 = *(const f32x4*)(sp + 4);
  bf16_t* xb = X + (size_t)row * (size_t)(128 << lgnh) + (h << 7) + d0;
  bf16x8 x1 = *(const bf16x8*)xb;
  bf16x8 x2 = *(const bf16x8*)(xb + 64);
  bf16x8 o1, o2;
#pragma unroll
  for (int e = 0; e < 8; ++e) {
    float c = e < 4 ? c0[e] : c1[e - 4];
    float s = e < 4 ? s0[e] : s1[e - 4];
    float a = (float)x1[e], bvl = (float)x2[e];
    o1[e] = (bf16_t)((a * c - bvl * s) * outScale);
    o2[e] = (bf16_t)((bvl * c + a * s) * outScale);
  }
  *(bf16x8*)xb = o1;
  *(bf16x8*)(xb + 64) = o2;
}

// ---------------------------------------------------------------------------
// Vp:[4096][512] -> Vt:[B*HKV][128][2048]  (Vt[bh][d][n] = Vp[b*2048+n][hkv*128+d])
// ---------------------------------------------------------------------------
__global__ void k_transpose_v(const bf16_t* __restrict__ Vp, bf16_t* __restrict__ Vt)
{
  __shared__ bf16_t tile[64][72];
  const int tid = threadIdx.x;
  const int r0 = blockIdx.x * 64;  // global row (b*2048+n)
  const int d0 = blockIdx.y * 64;  // col in [0,512)
  for (int r = 0; r < 2; ++r) {
    int n = r * 32 + (tid >> 3);
    int dc = (tid & 7) * 8;
    *(uint4*)&tile[n][dc] = *(const uint4*)(Vp + (size_t)(r0 + n) * KVD_ + d0 + dc);
  }
  __syncthreads();
  const int b = r0 >> 11;
  const int nseq = r0 & (N_ - 1);
  for (int r = 0; r < 2; ++r) {
    int dd = r * 32 + (tid >> 3);
    int nc = (tid & 7) * 8;
    int dglob = d0 + dd;
    int hkv = dglob >> 7, dloc = dglob & 127;
    union { bf16_t h[8]; uint4 v; } pk;
    for (int j = 0; j < 8; ++j) pk.h[j] = tile[nc + j][dd];
    size_t drow = (size_t)(b * HKV_ + hkv) * 128 + dloc;
    *(uint4*)(Vt + drow * N_ + nseq + nc) = pk.v;
  }
}

// ---------------------------------------------------------------------------
// Flash attention, causal GQA. Grid (16, B*HQ). Complementary pairing:
// bx = (y<16 ? 15-x : x) so the two blocks a CU hosts (same x, y and y+16)
// have tile counts summing to 34 -> balanced makespan. Block = 4 waves owning
// qtiles 4*bx..4*bx+3 of ONE (b,hq). Dbuf K/V staging; swapped-operand MFMA
// lane-local softmax with defer-max (T13); setprio; output in-place into Qp.
// ---------------------------------------------------------------------------
__global__ __launch_bounds__(256, 2) void k_attn(
    const bf16_t* __restrict__ Qp, const bf16_t* __restrict__ Kp,
    const bf16_t* __restrict__ Vt, bf16_t* __restrict__ AO)
{
  __shared__ bf16_t Ks[2][64 * 128];
  __shared__ bf16_t Vs[2][128 * 64];
  __shared__ bf16_t Ps[4][16 * 72];
  const int tid = threadIdx.x, lane = tid & 63, wave = tid >> 6;
  const int l15 = lane & 15, lg = lane >> 4;
  // complementary pairing: CU hosts (x,y) and (x,y+16) -> 34 tiles total
  const int bx = (blockIdx.y < 16) ? (15 - (int)blockIdx.x) : (int)blockIdx.x;
  const int qtile = bx * 4 + wave;
  const int bh = blockIdx.y;
  const int b = bh >> 4, hq = bh & 15, hkv = hq >> 2;

  // Q fragments: 2 row-frags x 4 k-steps (RoPE'd, scale folded)
  bf16x8 qf[2][4];
  for (int rf = 0; rf < 2; ++rf) {
    size_t qrow = (size_t)b * N_ + qtile * 32 + rf * 16 + l15;
    const uint8_t* qb = (const uint8_t*)Qp + (qrow * DIM_ + (size_t)hq * HD_) * 2 + lg * 16;
    for (int ks = 0; ks < 4; ++ks)
      qf[rf][ks] = *(const bf16x8*)(qb + ks * 64);
  }

  float m[2] = {-1e30f, -1e30f};
  float ln[2] = {0.f, 0.f};
  f32x4 o[2][8] = {};   // o[rf][db][rr]: q = l15 (col), d = db*16+lg*4+rr (row)

  const uint8_t* KpB = (const uint8_t*)Kp + ((size_t)b * N_ * KVD_ + (size_t)hkv * HD_) * 2;
  const uint8_t* VtB = (const uint8_t*)Vt + (size_t)(b * HKV_ + hkv) * HD_ * (size_t)N_ * 2;
  uint8_t* PwB = (uint8_t*)Ps[wave];

  const int Tw   = qtile / 2 + 1;     // this wave's causal tile count
  const int Tmax = 2 * bx + 2;        // block's tile count

  auto stage = [&](int buf, int t) {
    uint8_t* KsB = (uint8_t*)Ks[buf];
    uint8_t* VsB = (uint8_t*)Vs[buf];
#pragma unroll
    for (int r = 0; r < 4; ++r) {
      int o16 = r * 4096 + wave * 1024 + lane * 16;
      int row = o16 >> 8;
      int colB = (o16 & 255) ^ ((row & 7) << 4);
      ld_g2l(KsB + r * 4096 + wave * 1024,
             KpB + (size_t)(t * 64 + row) * (KVD_ * 2) + colB);
    }
#pragma unroll
    for (int r = 0; r < 4; ++r) {
      int o16 = r * 4096 + wave * 1024 + lane * 16;
      int dd = o16 >> 7;
      int colB = (o16 & 127) ^ ((dd & 7) << 4);
      ld_g2l(VsB + r * 4096 + wave * 1024,
             VtB + (size_t)dd * (N_ * 2) + t * 128 + colB);
    }
  };

  stage(0, 0);
  __syncthreads();
  int cur = 0;

  for (int t = 0; t < Tmax; ++t) {
    if (t + 1 < Tmax) stage(cur ^ 1, t + 1);   // prefetch next tile (async)

    if (t < Tw) {
      const uint8_t* KsB = (const uint8_t*)Ks[cur];
      const uint8_t* VsB = (const uint8_t*)Vs[cur];

      // S^T = K Q^T : s4[rf][kb], lane holds [key = kb*16+lg*4+rr][q = l15]
      f32x4 s4[2][4] = {};
      __builtin_amdgcn_s_setprio(1);
#pragma unroll
      for (int ks = 0; ks < 4; ++ks) {
        int koff = ks * 64 + lg * 16;
#pragma unroll
        for (int kb = 0; kb < 4; ++kb) {
          int row = kb * 16 + l15;
          bf16x8 kf = *(const bf16x8*)(KsB + row * 256 + (koff ^ ((row & 7) << 4)));
          s4[0][kb] = __builtin_amdgcn_mfma_f32_16x16x32_bf16(kf, qf[0][ks], s4[0][kb], 0, 0, 0);
          s4[1][kb] = __builtin_amdgcn_mfma_f32_16x16x32_bf16(kf, qf[1][ks], s4[1][kb], 0, 0, 0);
        }
      }
      __builtin_amdgcn_s_setprio(0);

      // causal mask on this wave's last tile: key > query -> -inf
      if (t == Tw - 1) {
#pragma unroll
        for (int rf = 0; rf < 2; ++rf) {
          int q = qtile * 32 + rf * 16 + l15;
#pragma unroll
          for (int kb = 0; kb < 4; ++kb) {
            int key = t * 64 + kb * 16 + lg * 4;
#pragma unroll
            for (int rr = 0; rr < 4; ++rr)
              if (key + rr > q) s4[rf][kb][rr] = -1e30f;
          }
        }
      }

      // lane-local online softmax + defer-max (T13) + P round-trip
      bf16x8 pf[2][2];
#pragma unroll
      for (int rf = 0; rf < 2; ++rf) {
        f32x4 mx = vmax4(vmax4(s4[rf][0], s4[rf][1]), vmax4(s4[rf][2], s4[rf][3]));
        float rm = fmaxf(fmaxf(mx[0], mx[1]), fmaxf(mx[2], mx[3]));
        rm = fmaxf(rm, __shfl_xor(rm, 16));
        rm = fmaxf(rm, __shfl_xor(rm, 32));

        // defer-max: if no lane's tile-max exceeds m+8, keep old max
        const bool defer = __all(rm <= m[rf] + 8.0f);
        float mn = defer ? m[rf] : fmaxf(m[rf], rm);
        float sc = defer ? 1.0f : __expf(m[rf] - mn);

        f32x4 p[4];
        f32x4 psum = {0.f, 0.f, 0.f, 0.f};
#pragma unroll
        for (int kb = 0; kb < 4; ++kb) {
#pragma unroll
          for (int rr = 0; rr < 4; ++rr)
            p[kb][rr] = __expf(s4[rf][kb][rr] - mn);
          psum += p[kb];
        }
        float rs = (psum[0] + psum[1]) + (psum[2] + psum[3]);
        rs += __shfl_xor(rs, 16);
        rs += __shfl_xor(rs, 32);
        ln[rf] = ln[rf] * sc + rs;
        m[rf] = mn;

        if (!defer) {
#pragma unroll
          for (int db = 0; db < 8; ++db) o[rf][db] *= sc;
        }

        // P -> per-wave LDS row q=l15 (4 packed 8B stores), then pf reads
#pragma unroll
        for (int kb = 0; kb < 4; ++kb) {
          union { bf16_t h[4]; uint2 u; } pk;
          pk.h[0] = (bf16_t)p[kb][0]; pk.h[1] = (bf16_t)p[kb][1];
          pk.h[2] = (bf16_t)p[kb][2]; pk.h[3] = (bf16_t)p[kb][3];
          *(uint2*)(PwB + l15 * 144 + kb * 32 + lg * 8) = pk.u;
        }
        pf[rf][0] = *(const bf16x8*)(PwB + l15 * 144 + lg * 16);
        pf[rf][1] = *(const bf16x8*)(PwB + l15 * 144 + 64 + lg * 16);
      }

      // O^T += V^T P^T : vf rows = d (shared by both rf)
      __builtin_amdgcn_s_setprio(1);
#pragma unroll
      for (int ks2 = 0; ks2 < 2; ++ks2) {
        int koff = ks2 * 64 + lg * 16;
#pragma unroll
        for (int db = 0; db < 8; ++db) {
          int dd = db * 16 + l15;
          bf16x8 vf = *(const bf16x8*)(VsB + dd * 128 + (koff ^ ((dd & 7) << 4)));
          o[0][db] = __builtin_amdgcn_mfma_f32_16x16x32_bf16(vf, pf[0][ks2], o[0][db], 0, 0, 0);
          o[1][db] = __builtin_amdgcn_mfma_f32_16x16x32_bf16(vf, pf[1][ks2], o[1][db], 0, 0, 0);
        }
      }
      __builtin_amdgcn_s_setprio(0);
    }

    __syncthreads();   // staged t+1 complete; all reads of buf[cur] done
    cur ^= 1;
  }

  // epilogue: lane q = l15; d = db*16 + lg*4 + rr -> packed 8B stores
#pragma unroll
  for (int rf = 0; rf < 2; ++rf) {
    float iv = 1.f / ln[rf];
    size_t qrow = (size_t)b * N_ + qtile * 32 + rf * 16 + l15;
    uint8_t* ob = (uint8_t*)(AO + qrow * DIM_ + (size_t)hq * HD_);
#pragma unroll
    for (int db = 0; db < 8; ++db) {
      union { bf16_t h[4]; uint2 u; } pk;
      pk.h[0] = (bf16_t)(o[rf][db][0] * iv);
      pk.h[1] = (bf16_t)(o[rf][db][1] * iv);
      pk.h[2] = (bf16_t)(o[rf][db][2] * iv);
      pk.h[3] = (bf16_t)(o[rf][db][3] * iv);
      *(uint2*)(ob + (db * 16 + lg * 4) * 2) = pk.u;
    }
  }
}

// ---------------------------------------------------------------------------
extern "C" void kernel_launch(void* const* d_in, const int* in_sizes, int n_in,
                              void* d_out, int out_size, void* d_ws, size_t ws_size,
                              hipStream_t stream)
{
  if (ws_size < (46u << 20)) return;  // proven sufficient in rounds 3-14

  const float* query = (const float*)d_in[0];
  const float* key   = (const float*)d_in[1];
  const float* value = (const float*)d_in[2];
  const float* Wq = (const float*)d_in[3];
  const float* bq = (const float*)d_in[4];
  const float* Wk = (const float*)d_in[5];
  const float* bk = (const float*)d_in[6];
  const float* Wv = (const float*)d_in[7];
  const float* bv = (const float*)d_in[8];
  const float* Wo = (const float*)d_in[9];
  const float* bo = (const float*)d_in[10];
  float* out = (float*)d_out;

  uint8_t* ws = (uint8_t*)d_ws;
  float*  cosT = (float*)(ws);                       // 0.5 MB
  float*  sinT = (float*)(ws + (512u << 10));        // 0.5 MB
  bf16_t* Qp   = (bf16_t*)(ws + (1u  << 20));        // 16 MB [4096][2048] (+ attn out)
  bf16_t* Kp   = (bf16_t*)(ws + (17u << 20));        // 4 MB  [4096][512]
  bf16_t* Vp   = (bf16_t*)(ws + (21u << 20));        // 4 MB  [4096][512]
  bf16_t* Vt   = (bf16_t*)(ws + (25u << 20));        // 4 MB  [8][128][2048]
  bf16_t* Wqb  = (bf16_t*)(ws + (29u << 20));        // 8 MB  [2048][2048]
  bf16_t* Wkb  = (bf16_t*)(ws + (37u << 20));        // 2 MB  [512][2048]
  bf16_t* Wvb  = (bf16_t*)(ws + (39u << 20));        // 2 MB  [512][2048]
  bf16_t* Wob  = (bf16_t*)(ws + (17u << 20));        // 8 MB, post-attn over Kp+Vp

  k_sincos<<<512, 256, 0, stream>>>(cosT, sinT);

  // convert Wq/Wk/Wv to bf16 (6.3M elems, one fused launch)
  k_cvt3<<<6144, 256, 0, stream>>>(Wq, Wqb, 4194304,
                                   Wk, Wkb, 1048576,
                                   Wv, Wvb, 1048576);

  // Q+K+V projections in one launch (z=0 Q, z=1 K, z=2 V), A = f32 reg-staged
  k_gemm_qkv<<<dim3(32, 16, 3), 256, 0, stream>>>(
      query, Wqb, bq, Qp, key, Wkb, bk, Kp, value, Wvb, bv, Vp);

  // vectorized RoPE: Q = 4096*16*8 threads, K = 4096*4*8 threads
  k_rope<<<2048, 256, 0, stream>>>(Qp, cosT, sinT, 4, SCALE_);
  k_rope<<<512,  256, 0, stream>>>(Kp, cosT, sinT, 2, 1.0f);

  k_transpose_v<<<dim3(64, 8), 256, 0, stream>>>(Vp, Vt);

  // flash attention: complementary pairing + dbuf staging, in-place output
  k_attn<<<dim3(16, 32), 256, 0, stream>>>(Qp, Kp, Vt, Qp);

  // convert Wo (after attn; reuses dead Kp/Vp space)
  k_cvt3<<<4096, 256, 0, stream>>>(Wo, Wob, 4194304,
                                   nullptr, nullptr, 0,
                                   nullptr, nullptr, 0);

  // Output projection: M=4096 N=2048 K=2048 (A bf16 g2l, W bf16 g2l, C f32)
  k_gemm_o<<<dim3(32, 16), 256, 0, stream>>>(Qp, Wob, bo, out);
}

// Round 16
// 213.581 us; speedup vs baseline: 1.2071x; 1.0212x over previous
//
#include <hip/hip_runtime.h>
#include <cstdint>

// ---------------------------------------------------------------------------
// GroupedQueryAttention: B=2 N=2048 DIM=2048 HQ=16 HKV=4 HD=128, causal, RoPE.
// f32 I/O, bf16 internals. Round 16:
//  - QKV: dual-bn blocks — one staged A-tile feeds TWO 128-col W-tiles
//    (64 MFMA/wave/round, A-staging amortized 2x, A re-reads halved).
//  - attention (complementary pairing + defer-max), rope, transpose, O-proj
//    unchanged from round 15.
// ---------------------------------------------------------------------------

typedef __bf16 bf16_t;
typedef __attribute__((ext_vector_type(8))) __bf16 bf16x8;
typedef __attribute__((ext_vector_type(4))) float f32x4;

#define B_    2
#define N_    2048
#define DIM_  2048
#define HQ_   16
#define HKV_  4
#define HD_   128
#define KVD_  512
#define SCALE_ 0.08838834764831845f  // 128^-0.5

// async global->LDS, 16B per lane. lds dest must be wave-uniform base.
static __device__ __forceinline__ void ld_g2l(void* lds, const void* g) {
  __builtin_amdgcn_global_load_lds((__attribute__((address_space(1))) void*)g,
                                   (__attribute__((address_space(3))) void*)lds,
                                   16, 0, 0);
}

static __device__ __forceinline__ f32x4 vmax4(f32x4 a, f32x4 b) {
  f32x4 r;
  r[0] = fmaxf(a[0], b[0]); r[1] = fmaxf(a[1], b[1]);
  r[2] = fmaxf(a[2], b[2]); r[3] = fmaxf(a[3], b[3]);
  return r;
}

// ---------------------------------------------------------------------------
// cos/sin table: [2048][64] each, f32.  inv_freq = 10000^(-i/64) (base_adj==1)
// ---------------------------------------------------------------------------
__global__ void k_sincos(float* __restrict__ cosT, float* __restrict__ sinT) {
  int idx = blockIdx.x * 256 + threadIdx.x;  // 2048*64
  int i = idx & 63;
  int n = idx >> 6;
  float inv = expf(-(float)i * (9.210340371976184f / 64.0f));  // ln(1e4)/64
  float ang = (float)n * inv;
  cosT[idx] = cosf(ang);
  sinT[idx] = sinf(ang);
}

// ---------------------------------------------------------------------------
// fused f32 -> bf16 conversion for up to three tensors (4 elems/thread)
// ---------------------------------------------------------------------------
__global__ void k_cvt3(const float* __restrict__ s0, bf16_t* __restrict__ d0, int n0,
                       const float* __restrict__ s1, bf16_t* __restrict__ d1, int n1,
                       const float* __restrict__ s2, bf16_t* __restrict__ d2, int n2)
{
  int i = (blockIdx.x * 256 + threadIdx.x) * 4;
  const float* s; bf16_t* d; int off;
  if (i < n0)                { s = s0; d = d0; off = i; }
  else if (i < n0 + n1)      { s = s1; d = d1; off = i - n0; }
  else if (i < n0 + n1 + n2) { s = s2; d = d2; off = i - n0 - n1; }
  else return;
  f32x4 v = *(const f32x4*)(s + off);
  union { bf16_t h[4]; uint2 u; } pk;
  pk.h[0] = (bf16_t)v[0]; pk.h[1] = (bf16_t)v[1];
  pk.h[2] = (bf16_t)v[2]; pk.h[3] = (bf16_t)v[3];
  *(uint2*)(d + off) = pk.u;
}

// ---------------------------------------------------------------------------
// QKV projections, dual-bn: each block stages one A f32 tile [128][64] and
// TWO W bf16 tiles (bn0=2*by, bn1=bn0+1), computing 128x256 of C per block.
// z=0 Q (by<8), z=1 K, z=2 V (by<2). BK=64, 4 waves each 64x(64+64).
// XOR swizzle byte^((row&7)<<4) on 128B rows.
// ---------------------------------------------------------------------------
__global__ __launch_bounds__(256, 2) void k_gemm_qkv(
    const float* __restrict__ q, const bf16_t* __restrict__ Wqb,
    const float* __restrict__ bq, bf16_t* __restrict__ Qp,
    const float* __restrict__ k, const bf16_t* __restrict__ Wkb,
    const float* __restrict__ bk, bf16_t* __restrict__ Kp,
    const float* __restrict__ v, const bf16_t* __restrict__ Wvb,
    const float* __restrict__ bv, bf16_t* __restrict__ Vp)
{
  __shared__ bf16_t As[128 * 64];
  __shared__ bf16_t Bs[2][128 * 64];
  const int z = blockIdx.z;
  if (z != 0 && blockIdx.y >= 2) return;
  const float* A; const bf16_t* W; const float* bias; bf16_t* C; int Nn;
  if (z == 0)      { A = q; W = Wqb; bias = bq; C = Qp; Nn = 2048; }
  else if (z == 1) { A = k; W = Wkb; bias = bk; C = Kp; Nn = 512; }
  else             { A = v; W = Wvb; bias = bv; C = Vp; Nn = 512; }

  const int tid  = threadIdx.x;
  const int lane = tid & 63;
  const int wave = tid >> 6;
  const int l15  = lane & 15;
  const int lg   = lane >> 4;
  const int bm = blockIdx.x;
  const int bn0 = blockIdx.y * 2, bn1 = bn0 + 1;
  const int wr = (wave >> 1) * 64, wc = (wave & 1) * 64;
  const int K = 2048;

  f32x4 acc0[4][4] = {};
  f32x4 acc1[4][4] = {};

  uint8_t* AsB = (uint8_t*)As;
  uint8_t* Bs0 = (uint8_t*)Bs[0];
  uint8_t* Bs1 = (uint8_t*)Bs[1];
  const uint8_t* Wb0 = (const uint8_t*)W + (size_t)(bn0 * 128) * K * 2;
  const uint8_t* Wb1 = (const uint8_t*)W + (size_t)(bn1 * 128) * K * 2;

  for (int k0 = 0; k0 < K; k0 += 64) {
    // two W tiles via g2l (async), pre-swizzled source
#pragma unroll
    for (int r = 0; r < 4; ++r) {
      int o = r * 4096 + wave * 1024 + lane * 16;
      int row = o >> 7;
      int colB = (o & 127) ^ ((row & 7) << 4);
      size_t goff = (size_t)row * (K * 2) + (size_t)k0 * 2 + colB;
      ld_g2l(Bs0 + r * 4096 + wave * 1024, Wb0 + goff);
      ld_g2l(Bs1 + r * 4096 + wave * 1024, Wb1 + goff);
    }
    // A tile: f32 load + cvt + swizzled LDS write
#pragma unroll
    for (int i = 0; i < 4; ++i) {
      int c = i * 256 + tid;
      int row = c >> 3;            // 0..127
      int k8  = (c & 7) * 8;       // element offset within K-tile
      const float* ap = A + (size_t)(bm * 128 + row) * K + k0 + k8;
      f32x4 alo = *(const f32x4*)ap;
      f32x4 ahi = *(const f32x4*)(ap + 4);
      bf16x8 va;
      va[0] = (bf16_t)alo[0]; va[1] = (bf16_t)alo[1];
      va[2] = (bf16_t)alo[2]; va[3] = (bf16_t)alo[3];
      va[4] = (bf16_t)ahi[0]; va[5] = (bf16_t)ahi[1];
      va[6] = (bf16_t)ahi[2]; va[7] = (bf16_t)ahi[3];
      int sw = (k8 * 2) ^ ((row & 7) << 4);
      *(bf16x8*)(AsB + row * 128 + sw) = va;
    }
    __syncthreads();
    __builtin_amdgcn_s_setprio(1);
#pragma unroll
    for (int kk = 0; kk < 2; ++kk) {
      const int koff = kk * 64 + (lg << 4);
      bf16x8 fa[4], fb[4];
#pragma unroll
      for (int fi = 0; fi < 4; ++fi) {
        int row = wr + fi * 16 + l15;
        fa[fi] = *(const bf16x8*)(AsB + row * 128 + (koff ^ ((row & 7) << 4)));
      }
#pragma unroll
      for (int fj = 0; fj < 4; ++fj) {
        int row = wc + fj * 16 + l15;
        fb[fj] = *(const bf16x8*)(Bs0 + row * 128 + (koff ^ ((row & 7) << 4)));
      }
#pragma unroll
      for (int fi = 0; fi < 4; ++fi)
#pragma unroll
        for (int fj = 0; fj < 4; ++fj)
          acc0[fi][fj] = __builtin_amdgcn_mfma_f32_16x16x32_bf16(
              fa[fi], fb[fj], acc0[fi][fj], 0, 0, 0);
#pragma unroll
      for (int fj = 0; fj < 4; ++fj) {
        int row = wc + fj * 16 + l15;
        fb[fj] = *(const bf16x8*)(Bs1 + row * 128 + (koff ^ ((row & 7) << 4)));
      }
#pragma unroll
      for (int fi = 0; fi < 4; ++fi)
#pragma unroll
        for (int fj = 0; fj < 4; ++fj)
          acc1[fi][fj] = __builtin_amdgcn_mfma_f32_16x16x32_bf16(
              fa[fi], fb[fj], acc1[fi][fj], 0, 0, 0);
    }
    __builtin_amdgcn_s_setprio(0);
    __syncthreads();
  }

  // epilogue: C/D layout col=lane&15, row=(lane>>4)*4+r; both bn halves
  const int r0 = lg * 4;
#pragma unroll
  for (int fi = 0; fi < 4; ++fi) {
#pragma unroll
    for (int rr = 0; rr < 4; ++rr) {
      int grow = bm * 128 + wr + fi * 16 + r0 + rr;
      size_t rowoff = (size_t)grow * Nn;
#pragma unroll
      for (int fj = 0; fj < 4; ++fj) {
        int gc0 = bn0 * 128 + wc + fj * 16 + l15;
        int gc1 = bn1 * 128 + wc + fj * 16 + l15;
        C[rowoff + gc0] = (bf16_t)(acc0[fi][fj][rr] + bias[gc0]);
        C[rowoff + gc1] = (bf16_t)(acc1[fi][fj][rr] + bias[gc1]);
      }
    }
  }
}

// ---------------------------------------------------------------------------
// O projection (r10 body): A bf16 g2l, W bf16 g2l, C f32. 128x128, BK=64.
// ---------------------------------------------------------------------------
__global__ __launch_bounds__(256, 4) void k_gemm_o(
    const bf16_t* __restrict__ Ain, const bf16_t* __restrict__ Wob,
    const float* __restrict__ bo, float* __restrict__ out)
{
  __shared__ bf16_t As[128 * 64];
  __shared__ bf16_t Bs[128 * 64];
  const int tid  = threadIdx.x;
  const int lane = tid & 63;
  const int wave = tid >> 6;
  const int l15  = lane & 15;
  const int lg   = lane >> 4;
  const int bm = blockIdx.x, bn = blockIdx.y;
  const int wr = (wave >> 1) * 64, wc = (wave & 1) * 64;
  const int K = 2048, N = 2048;

  f32x4 acc[4][4] = {};
  uint8_t* AsB = (uint8_t*)As;
  uint8_t* BsB = (uint8_t*)Bs;
  const uint8_t* Wbase = (const uint8_t*)Wob + (size_t)(bn * 128) * K * 2;
  const uint8_t* Abase = (const uint8_t*)Ain + (size_t)(bm * 128) * K * 2;

  for (int k0 = 0; k0 < K; k0 += 64) {
    for (int r = 0; r < 4; ++r) {
      int o = r * 4096 + wave * 1024 + lane * 16;
      int row = o >> 7;
      int colB = (o & 127) ^ ((row & 7) << 4);
      size_t goff = (size_t)row * (K * 2) + (size_t)k0 * 2 + colB;
      ld_g2l(BsB + r * 4096 + wave * 1024, Wbase + goff);
      ld_g2l(AsB + r * 4096 + wave * 1024, Abase + goff);
    }
    __syncthreads();
    for (int kk = 0; kk < 2; ++kk) {
      const int koff = kk * 64 + (lg << 4);
      bf16x8 fa[4], fb[4];
      for (int fi = 0; fi < 4; ++fi) {
        int row = wr + fi * 16 + l15;
        fa[fi] = *(const bf16x8*)(AsB + row * 128 + (koff ^ ((row & 7) << 4)));
      }
      for (int fj = 0; fj < 4; ++fj) {
        int row = wc + fj * 16 + l15;
        fb[fj] = *(const bf16x8*)(BsB + row * 128 + (koff ^ ((row & 7) << 4)));
      }
      for (int fi = 0; fi < 4; ++fi)
        for (int fj = 0; fj < 4; ++fj)
          acc[fi][fj] = __builtin_amdgcn_mfma_f32_16x16x32_bf16(
              fa[fi], fb[fj], acc[fi][fj], 0, 0, 0);
    }
    __syncthreads();
  }

  const int r0 = lg * 4;
  for (int fi = 0; fi < 4; ++fi) {
    for (int rr = 0; rr < 4; ++rr) {
      int grow = bm * 128 + wr + fi * 16 + r0 + rr;
      size_t rowoff = (size_t)grow * N;
      for (int fj = 0; fj < 4; ++fj) {
        int gcol = bn * 128 + wc + fj * 16 + l15;
        out[rowoff + gcol] = acc[fi][fj][rr] + bo[gcol];
      }
    }
  }
}

// ---------------------------------------------------------------------------
// RoPE in-place on X:[4096][nheads*128] bf16, vectorized (8 pairs/thread).
// ---------------------------------------------------------------------------
__global__ void k_rope(bf16_t* __restrict__ X, const float* __restrict__ cosT,
                       const float* __restrict__ sinT, int lgnh, float outScale)
{
  int idx = blockIdx.x * 256 + threadIdx.x;
  int j = idx & 7;                       // d0 = j*8
  int h = (idx >> 3) & ((1 << lgnh) - 1);
  int row = idx >> (3 + lgnh);
  int n = row & (N_ - 1);
  int d0 = j * 8;
  const float* cp = cosT + (n << 6) + d0;
  const float* sp = sinT + (n << 6) + d0;
  f32x4 c0 = *(const f32x4*)cp,  c1 = *(const f32x4*)(cp + 4);
  f32x4 s0 = *(const f32x4*)sp,  s1 = *(const f32x4*)(sp + 4);
  bf16_t* xb = X + (size_t)row * (size_t)(128 << lgnh) + (h << 7) + d0;
  bf16x8 x1 = *(const bf16x8*)xb;
  bf16x8 x2 = *(const bf16x8*)(xb + 64);
  bf16x8 o1, o2;
#pragma unroll
  for (int e = 0; e < 8; ++e) {
    float c = e < 4 ? c0[e] : c1[e - 4];
    float s = e < 4 ? s0[e] : s1[e - 4];
    float a = (float)x1[e], bvl = (float)x2[e];
    o1[e] = (bf16_t)((a * c - bvl * s) * outScale);
    o2[e] = (bf16_t)((bvl * c + a * s) * outScale);
  }
  *(bf16x8*)xb = o1;
  *(bf16x8*)(xb + 64) = o2;
}

// ---------------------------------------------------------------------------
// Vp:[4096][512] -> Vt:[B*HKV][128][2048]  (Vt[bh][d][n] = Vp[b*2048+n][hkv*128+d])
// ---------------------------------------------------------------------------
__global__ void k_transpose_v(const bf16_t* __restrict__ Vp, bf16_t* __restrict__ Vt)
{
  __shared__ bf16_t tile[64][72];
  const int tid = threadIdx.x;
  const int r0 = blockIdx.x * 64;  // global row (b*2048+n)
  const int d0 = blockIdx.y * 64;  // col in [0,512)
  for (int r = 0; r < 2; ++r) {
    int n = r * 32 + (tid >> 3);
    int dc = (tid & 7) * 8;
    *(uint4*)&tile[n][dc] = *(const uint4*)(Vp + (size_t)(r0 + n) * KVD_ + d0 + dc);
  }
  __syncthreads();
  const int b = r0 >> 11;
  const int nseq = r0 & (N_ - 1);
  for (int r = 0; r < 2; ++r) {
    int dd = r * 32 + (tid >> 3);
    int nc = (tid & 7) * 8;
    int dglob = d0 + dd;
    int hkv = dglob >> 7, dloc = dglob & 127;
    union { bf16_t h[8]; uint4 v; } pk;
    for (int j = 0; j < 8; ++j) pk.h[j] = tile[nc + j][dd];
    size_t drow = (size_t)(b * HKV_ + hkv) * 128 + dloc;
    *(uint4*)(Vt + drow * N_ + nseq + nc) = pk.v;
  }
}

// ---------------------------------------------------------------------------
// Flash attention, causal GQA (r15): complementary pairing, dbuf staging,
// swapped-operand lane-local softmax + defer-max, setprio, in-place output.
// ---------------------------------------------------------------------------
__global__ __launch_bounds__(256, 2) void k_attn(
    const bf16_t* __restrict__ Qp, const bf16_t* __restrict__ Kp,
    const bf16_t* __restrict__ Vt, bf16_t* __restrict__ AO)
{
  __shared__ bf16_t Ks[2][64 * 128];
  __shared__ bf16_t Vs[2][128 * 64];
  __shared__ bf16_t Ps[4][16 * 72];
  const int tid = threadIdx.x, lane = tid & 63, wave = tid >> 6;
  const int l15 = lane & 15, lg = lane >> 4;
  const int bx = (blockIdx.y < 16) ? (15 - (int)blockIdx.x) : (int)blockIdx.x;
  const int qtile = bx * 4 + wave;
  const int bh = blockIdx.y;
  const int b = bh >> 4, hq = bh & 15, hkv = hq >> 2;

  bf16x8 qf[2][4];
  for (int rf = 0; rf < 2; ++rf) {
    size_t qrow = (size_t)b * N_ + qtile * 32 + rf * 16 + l15;
    const uint8_t* qb = (const uint8_t*)Qp + (qrow * DIM_ + (size_t)hq * HD_) * 2 + lg * 16;
    for (int ks = 0; ks < 4; ++ks)
      qf[rf][ks] = *(const bf16x8*)(qb + ks * 64);
  }

  float m[2] = {-1e30f, -1e30f};
  float ln[2] = {0.f, 0.f};
  f32x4 o[2][8] = {};

  const uint8_t* KpB = (const uint8_t*)Kp + ((size_t)b * N_ * KVD_ + (size_t)hkv * HD_) * 2;
  const uint8_t* VtB = (const uint8_t*)Vt + (size_t)(b * HKV_ + hkv) * HD_ * (size_t)N_ * 2;
  uint8_t* PwB = (uint8_t*)Ps[wave];

  const int Tw   = qtile / 2 + 1;
  const int Tmax = 2 * bx + 2;

  auto stage = [&](int buf, int t) {
    uint8_t* KsB = (uint8_t*)Ks[buf];
    uint8_t* VsB = (uint8_t*)Vs[buf];
#pragma unroll
    for (int r = 0; r < 4; ++r) {
      int o16 = r * 4096 + wave * 1024 + lane * 16;
      int row = o16 >> 8;
      int colB = (o16 & 255) ^ ((row & 7) << 4);
      ld_g2l(KsB + r * 4096 + wave * 1024,
             KpB + (size_t)(t * 64 + row) * (KVD_ * 2) + colB);
    }
#pragma unroll
    for (int r = 0; r < 4; ++r) {
      int o16 = r * 4096 + wave * 1024 + lane * 16;
      int dd = o16 >> 7;
      int colB = (o16 & 127) ^ ((dd & 7) << 4);
      ld_g2l(VsB + r * 4096 + wave * 1024,
             VtB + (size_t)dd * (N_ * 2) + t * 128 + colB);
    }
  };

  stage(0, 0);
  __syncthreads();
  int cur = 0;

  for (int t = 0; t < Tmax; ++t) {
    if (t + 1 < Tmax) stage(cur ^ 1, t + 1);

    if (t < Tw) {
      const uint8_t* KsB = (const uint8_t*)Ks[cur];
      const uint8_t* VsB = (const uint8_t*)Vs[cur];

      f32x4 s4[2][4] = {};
      __builtin_amdgcn_s_setprio(1);
#pragma unroll
      for (int ks = 0; ks < 4; ++ks) {
        int koff = ks * 64 + lg * 16;
#pragma unroll
        for (int kb = 0; kb < 4; ++kb) {
          int row = kb * 16 + l15;
          bf16x8 kf = *(const bf16x8*)(KsB + row * 256 + (koff ^ ((row & 7) << 4)));
          s4[0][kb] = __builtin_amdgcn_mfma_f32_16x16x32_bf16(kf, qf[0][ks], s4[0][kb], 0, 0, 0);
          s4[1][kb] = __builtin_amdgcn_mfma_f32_16x16x32_bf16(kf, qf[1][ks], s4[1][kb], 0, 0, 0);
        }
      }
      __builtin_amdgcn_s_setprio(0);

      if (t == Tw - 1) {
#pragma unroll
        for (int rf = 0; rf < 2; ++rf) {
          int q = qtile * 32 + rf * 16 + l15;
#pragma unroll
          for (int kb = 0; kb < 4; ++kb) {
            int key = t * 64 + kb * 16 + lg * 4;
#pragma unroll
            for (int rr = 0; rr < 4; ++rr)
              if (key + rr > q) s4[rf][kb][rr] = -1e30f;
          }
        }
      }

      bf16x8 pf[2][2];
#pragma unroll
      for (int rf = 0; rf < 2; ++rf) {
        f32x4 mx = vmax4(vmax4(s4[rf][0], s4[rf][1]), vmax4(s4[rf][2], s4[rf][3]));
        float rm = fmaxf(fmaxf(mx[0], mx[1]), fmaxf(mx[2], mx[3]));
        rm = fmaxf(rm, __shfl_xor(rm, 16));
        rm = fmaxf(rm, __shfl_xor(rm, 32));

        const bool defer = __all(rm <= m[rf] + 8.0f);
        float mn = defer ? m[rf] : fmaxf(m[rf], rm);
        float sc = defer ? 1.0f : __expf(m[rf] - mn);

        f32x4 p[4];
        f32x4 psum = {0.f, 0.f, 0.f, 0.f};
#pragma unroll
        for (int kb = 0; kb < 4; ++kb) {
#pragma unroll
          for (int rr = 0; rr < 4; ++rr)
            p[kb][rr] = __expf(s4[rf][kb][rr] - mn);
          psum += p[kb];
        }
        float rs = (psum[0] + psum[1]) + (psum[2] + psum[3]);
        rs += __shfl_xor(rs, 16);
        rs += __shfl_xor(rs, 32);
        ln[rf] = ln[rf] * sc + rs;
        m[rf] = mn;

        if (!defer) {
#pragma unroll
          for (int db = 0; db < 8; ++db) o[rf][db] *= sc;
        }

#pragma unroll
        for (int kb = 0; kb < 4; ++kb) {
          union { bf16_t h[4]; uint2 u; } pk;
          pk.h[0] = (bf16_t)p[kb][0]; pk.h[1] = (bf16_t)p[kb][1];
          pk.h[2] = (bf16_t)p[kb][2]; pk.h[3] = (bf16_t)p[kb][3];
          *(uint2*)(PwB + l15 * 144 + kb * 32 + lg * 8) = pk.u;
        }
        pf[rf][0] = *(const bf16x8*)(PwB + l15 * 144 + lg * 16);
        pf[rf][1] = *(const bf16x8*)(PwB + l15 * 144 + 64 + lg * 16);
      }

      __builtin_amdgcn_s_setprio(1);
#pragma unroll
      for (int ks2 = 0; ks2 < 2; ++ks2) {
        int koff = ks2 * 64 + lg * 16;
#pragma unroll
        for (int db = 0; db < 8; ++db) {
          int dd = db * 16 + l15;
          bf16x8 vf = *(const bf16x8*)(VsB + dd * 128 + (koff ^ ((dd & 7) << 4)));
          o[0][db] = __builtin_amdgcn_mfma_f32_16x16x32_bf16(vf, pf[0][ks2], o[0][db], 0, 0, 0);
          o[1][db] = __builtin_amdgcn_mfma_f32_16x16x32_bf16(vf, pf[1][ks2], o[1][db], 0, 0, 0);
        }
      }
      __builtin_amdgcn_s_setprio(0);
    }

    __syncthreads();
    cur ^= 1;
  }

#pragma unroll
  for (int rf = 0; rf < 2; ++rf) {
    float iv = 1.f / ln[rf];
    size_t qrow = (size_t)b * N_ + qtile * 32 + rf * 16 + l15;
    uint8_t* ob = (uint8_t*)(AO + qrow * DIM_ + (size_t)hq * HD_);
#pragma unroll
    for (int db = 0; db < 8; ++db) {
      union { bf16_t h[4]; uint2 u; } pk;
      pk.h[0] = (bf16_t)(o[rf][db][0] * iv);
      pk.h[1] = (bf16_t)(o[rf][db][1] * iv);
      pk.h[2] = (bf16_t)(o[rf][db][2] * iv);
      pk.h[3] = (bf16_t)(o[rf][db][3] * iv);
      *(uint2*)(ob + (db * 16 + lg * 4) * 2) = pk.u;
    }
  }
}

// ---------------------------------------------------------------------------
extern "C" void kernel_launch(void* const* d_in, const int* in_sizes, int n_in,
                              void* d_out, int out_size, void* d_ws, size_t ws_size,
                              hipStream_t stream)
{
  if (ws_size < (46u << 20)) return;  // proven sufficient in rounds 3-15

  const float* query = (const float*)d_in[0];
  const float* key   = (const float*)d_in[1];
  const float* value = (const float*)d_in[2];
  const float* Wq = (const float*)d_in[3];
  const float* bq = (const float*)d_in[4];
  const float* Wk = (const float*)d_in[5];
  const float* bk = (const float*)d_in[6];
  const float* Wv = (const float*)d_in[7];
  const float* bv = (const float*)d_in[8];
  const float* Wo = (const float*)d_in[9];
  const float* bo = (const float*)d_in[10];
  float* out = (float*)d_out;

  uint8_t* ws = (uint8_t*)d_ws;
  float*  cosT = (float*)(ws);                       // 0.5 MB
  float*  sinT = (float*)(ws + (512u << 10));        // 0.5 MB
  bf16_t* Qp   = (bf16_t*)(ws + (1u  << 20));        // 16 MB [4096][2048] (+ attn out)
  bf16_t* Kp   = (bf16_t*)(ws + (17u << 20));        // 4 MB  [4096][512]
  bf16_t* Vp   = (bf16_t*)(ws + (21u << 20));        // 4 MB  [4096][512]
  bf16_t* Vt   = (bf16_t*)(ws + (25u << 20));        // 4 MB  [8][128][2048]
  bf16_t* Wqb  = (bf16_t*)(ws + (29u << 20));        // 8 MB  [2048][2048]
  bf16_t* Wkb  = (bf16_t*)(ws + (37u << 20));        // 2 MB  [512][2048]
  bf16_t* Wvb  = (bf16_t*)(ws + (39u << 20));        // 2 MB  [512][2048]
  bf16_t* Wob  = (bf16_t*)(ws + (17u << 20));        // 8 MB, post-attn over Kp+Vp

  k_sincos<<<512, 256, 0, stream>>>(cosT, sinT);

  // convert Wq/Wk/Wv to bf16 (6.3M elems, one fused launch)
  k_cvt3<<<6144, 256, 0, stream>>>(Wq, Wqb, 4194304,
                                   Wk, Wkb, 1048576,
                                   Wv, Wvb, 1048576);

  // Q+K+V projections, dual-bn (z=0 Q by<8, z=1 K, z=2 V by<2)
  k_gemm_qkv<<<dim3(32, 8, 3), 256, 0, stream>>>(
      query, Wqb, bq, Qp, key, Wkb, bk, Kp, value, Wvb, bv, Vp);

  // vectorized RoPE: Q = 4096*16*8 threads, K = 4096*4*8 threads
  k_rope<<<2048, 256, 0, stream>>>(Qp, cosT, sinT, 4, SCALE_);
  k_rope<<<512,  256, 0, stream>>>(Kp, cosT, sinT, 2, 1.0f);

  k_transpose_v<<<dim3(64, 8), 256, 0, stream>>>(Vp, Vt);

  // flash attention: complementary pairing + dbuf staging, in-place output
  k_attn<<<dim3(16, 32), 256, 0, stream>>>(Qp, Kp, Vt, Qp);

  // convert Wo (after attn; reuses dead Kp/Vp space)
  k_cvt3<<<4096, 256, 0, stream>>>(Wo, Wob, 4194304,
                                   nullptr, nullptr, 0,
                                   nullptr, nullptr, 0);

  // Output projection: M=4096 N=2048 K=2048 (A bf16 g2l, W bf16 g2l, C f32)
  k_gemm_o<<<dim3(32, 16), 256, 0, stream>>>(Qp, Wob, bo, out);
}